// Round 1
// 805.299 us; speedup vs baseline: 1.0064x; 1.0064x over previous
//
#include <hip/hip_runtime.h>
#include <hip/hip_bf16.h>

// LoRA transformer: L=8, D=1024, H=16, HD=64, R=16, B=2, S=1024.
// bf16 MFMA everywhere, fp32 residual stream.
// R7: attn -> 512 blocks (2 waves/SIMD; one 64-row q-block each, complementary
// load mapping qblk = bh<16 ? x : 15-x); merge_T batched over all 8 layers
// (2 dispatches, gridDim.z=8); convert fused with residual-copy.
// R8: merge_T -> hoist the 16 Bm float4 vectors into registers (they are
// row-loop-invariant; compiler wasn't hoisting them, causing 64 float4
// L1 re-loads/thread = ~1.6 GB of L1 traffic); A row loaded as 4x float4.

typedef unsigned short ushort_t;
typedef __attribute__((ext_vector_type(8))) short bf16x8;
typedef __attribute__((ext_vector_type(4))) float f32x4;

__device__ __forceinline__ unsigned short f2bf(float f) {
    union { float f; unsigned int u; } x; x.f = f;
    unsigned int r = x.u + 0x7fffu + ((x.u >> 16) & 1u);  // RNE
    return (unsigned short)(r >> 16);
}

__device__ __forceinline__ f32x4 mfma16(bf16x8 a, bf16x8 b, f32x4 c) {
    return __builtin_amdgcn_mfma_f32_16x16x32_bf16(a, b, c, 0, 0, 0);
}

typedef const __attribute__((address_space(1))) unsigned int* gas_ptr;
typedef __attribute__((address_space(3))) unsigned int* las_ptr;
// async global->LDS, 16B/lane; LDS dest = wave-uniform base + lane*16 (m104/m108)
__device__ __forceinline__ void lds_stage16(const void* g, void* l) {
    __builtin_amdgcn_global_load_lds((gas_ptr)(unsigned long long)g,
                                     (las_ptr)(unsigned int)(unsigned long long)l,
                                     16, 0, 0);
}

// DPP 16-lane row reductions (row_ror:S = 0x120+S)
#define RORMAX(x, C)                                                           \
    x = fmaxf(x, __int_as_float(__builtin_amdgcn_mov_dpp(                      \
                     __float_as_int(x), C, 0xf, 0xf, false)));
#define RORADD(x, C)                                                           \
    x += __int_as_float(__builtin_amdgcn_mov_dpp(                              \
        __float_as_int(x), C, 0xf, 0xf, false));

// ---------------- x -> (h_f32 copy, h_bf16) ----------------
__global__ __launch_bounds__(256) void convert_x(
    const float4* __restrict__ in, float4* __restrict__ outF,
    ushort4* __restrict__ outB, int n4) {
    int i = blockIdx.x * 256 + threadIdx.x;
    if (i < n4) {
        float4 v = in[i];
        outF[i] = v;
        ushort4 o;
        o.x = f2bf(v.x); o.y = f2bf(v.y); o.z = f2bf(v.z); o.w = f2bf(v.w);
        outB[i] = o;
    }
}

// ------------- LoRA merge + transpose, batched over layers (z) -------------
// WT[z][n][k] = bf16(W[z][k][n] + A[z][k][:] . B[z][:][n])
__global__ __launch_bounds__(256) void merge_T(
    const float* __restrict__ W, const float* __restrict__ A,
    const float* __restrict__ Bm, unsigned short* __restrict__ WT, int N) {
    __shared__ float t[32][132];
    const int z = blockIdx.z;
    W  += (size_t)z * 1024 * N;
    A  += (size_t)z * 1024 * 16;
    Bm += (size_t)z * 16 * N;
    WT += (size_t)z * N * 1024;
    int j0 = blockIdx.x * 128, i0 = blockIdx.y * 32;
    int tx = threadIdx.x & 31, ty = threadIdx.x >> 5;  // 32 x 8
    // B columns for this thread are row-loop-invariant: load ONCE (64 VGPRs).
    float4 bv[16];
    #pragma unroll
    for (int r = 0; r < 16; r++)
        bv[r] = *(const float4*)&Bm[(size_t)r * N + j0 + tx * 4];
    #pragma unroll
    for (int ii0 = 0; ii0 < 4; ii0++) {
        int ii = ty + ii0 * 8;
        int i = i0 + ii;
        float4 acc = *(const float4*)&W[(size_t)i * N + j0 + tx * 4];
        const float4* Ar = (const float4*)&A[i * 16];
        float4 a0 = Ar[0], a1 = Ar[1], a2 = Ar[2], a3 = Ar[3];
        float av[16] = {a0.x, a0.y, a0.z, a0.w, a1.x, a1.y, a1.z, a1.w,
                        a2.x, a2.y, a2.z, a2.w, a3.x, a3.y, a3.z, a3.w};
        #pragma unroll
        for (int r = 0; r < 16; r++) {
            acc.x += av[r] * bv[r].x; acc.y += av[r] * bv[r].y;
            acc.z += av[r] * bv[r].z; acc.w += av[r] * bv[r].w;
        }
        *(float4*)&t[ii][tx * 4] = acc;
    }
    __syncthreads();
    int jj = threadIdx.x >> 1, half = threadIdx.x & 1;
    bf16x8 o0, o1;
    #pragma unroll
    for (int c = 0; c < 8; c++) o0[c] = (short)f2bf(t[half * 16 + c][jj]);
    #pragma unroll
    for (int c = 0; c < 8; c++) o1[c] = (short)f2bf(t[half * 16 + 8 + c][jj]);
    unsigned short* dst = &WT[(size_t)(j0 + jj) * 1024 + i0 + half * 16];
    *(bf16x8*)dst = o0;
    *(bf16x8*)(dst + 8) = o1;
}

// ------------- GEMM 128x128, BK=64 (two m97-shape sub-buffers/barrier) -------------
__global__ __launch_bounds__(256) void gemm_bf16_128(
    const unsigned short* __restrict__ A,   // [M][K]
    const unsigned short* __restrict__ BT,  // [N][K]
    unsigned short* __restrict__ outB,      // bf16 out
    int M, int N, int K, int scaleq) {
    __shared__ __align__(16) unsigned short As[2][128 * 32];
    __shared__ __align__(16) unsigned short Bs[2][128 * 32];
    const int tid = threadIdx.x;
    const int m0 = blockIdx.y * 128, n0 = blockIdx.x * 128;
    const int w = tid >> 6, lane = tid & 63;
    const int wm = (w >> 1) * 64, wn = (w & 1) * 64;
    const int lr = lane & 15, quad = lane >> 4;
    const int srow = w * 16 + (lane >> 2);
    const int skof = (lane & 3) * 8;

    f32x4 acc[4][4] = {};

    for (int k0 = 0; k0 < K; k0 += 64) {
        __syncthreads();
        #pragma unroll
        for (int h = 0; h < 2; h++) {
            lds_stage16(A  + (size_t)(m0 + srow)      * K + k0 + h * 32 + skof,
                        (char*)As[h] + w * 1024);
            lds_stage16(A  + (size_t)(m0 + 64 + srow) * K + k0 + h * 32 + skof,
                        (char*)As[h] + 4096 + w * 1024);
            lds_stage16(BT + (size_t)(n0 + srow)      * K + k0 + h * 32 + skof,
                        (char*)Bs[h] + w * 1024);
            lds_stage16(BT + (size_t)(n0 + 64 + srow) * K + k0 + h * 32 + skof,
                        (char*)Bs[h] + 4096 + w * 1024);
        }
        __syncthreads();

        #pragma unroll
        for (int h = 0; h < 2; h++) {
            bf16x8 af[4], bfr[4];
            #pragma unroll
            for (int i = 0; i < 4; i++) {
                af[i]  = *(const bf16x8*)&As[h][(wm + i * 16 + lr) * 32 + quad * 8];
                bfr[i] = *(const bf16x8*)&Bs[h][(wn + i * 16 + lr) * 32 + quad * 8];
            }
            #pragma unroll
            for (int i = 0; i < 4; i++)
                #pragma unroll
                for (int j = 0; j < 4; j++)
                    acc[i][j] = mfma16(af[i], bfr[j], acc[i][j]);
        }
    }
    #pragma unroll
    for (int i = 0; i < 4; i++)
        #pragma unroll
        for (int j = 0; j < 4; j++)
            #pragma unroll
            for (int r = 0; r < 4; r++) {
                int row = m0 + wm + i * 16 + quad * 4 + r;
                int col = n0 + wn + j * 16 + lr;
                float v = acc[i][j][r];
                if (scaleq && col < 1024) v *= 0.125f;
                outB[(size_t)row * N + col] = f2bf(v);
            }
}

// ------------- GEMM 64x64, BK=64 (proj: 512 blocks, 2/CU) + residual -------------
__global__ __launch_bounds__(256) void gemm_bf16_64(
    const unsigned short* __restrict__ A,   // [M][K]
    const unsigned short* __restrict__ BT,  // [N][K]
    const float* __restrict__ res,          // [M][N] residual
    float* __restrict__ outF,               // fp32 out
    unsigned short* __restrict__ outB,      // bf16 out
    int M, int N, int K) {
    __shared__ __align__(16) unsigned short As[2][64 * 32];
    __shared__ __align__(16) unsigned short Bs[2][64 * 32];
    const int tid = threadIdx.x;
    const int m0 = blockIdx.y * 64, n0 = blockIdx.x * 64;
    const int w = tid >> 6, lane = tid & 63;
    const int wm = (w >> 1) * 32, wn = (w & 1) * 32;
    const int lr = lane & 15, quad = lane >> 4;
    const int srow = w * 16 + (lane >> 2);
    const int skof = (lane & 3) * 8;

    f32x4 acc[2][2] = {};

    for (int k0 = 0; k0 < K; k0 += 64) {
        __syncthreads();
        #pragma unroll
        for (int h = 0; h < 2; h++) {
            lds_stage16(A  + (size_t)(m0 + srow) * K + k0 + h * 32 + skof,
                        (char*)As[h] + w * 1024);
            lds_stage16(BT + (size_t)(n0 + srow) * K + k0 + h * 32 + skof,
                        (char*)Bs[h] + w * 1024);
        }
        __syncthreads();

        #pragma unroll
        for (int h = 0; h < 2; h++) {
            bf16x8 af[2], bfr[2];
            #pragma unroll
            for (int i = 0; i < 2; i++) {
                af[i]  = *(const bf16x8*)&As[h][(wm + i * 16 + lr) * 32 + quad * 8];
                bfr[i] = *(const bf16x8*)&Bs[h][(wn + i * 16 + lr) * 32 + quad * 8];
            }
            #pragma unroll
            for (int i = 0; i < 2; i++)
                #pragma unroll
                for (int j = 0; j < 2; j++)
                    acc[i][j] = mfma16(af[i], bfr[j], acc[i][j]);
        }
    }
    #pragma unroll
    for (int i = 0; i < 2; i++)
        #pragma unroll
        for (int j = 0; j < 2; j++)
            #pragma unroll
            for (int r = 0; r < 4; r++) {
                int row = m0 + wm + i * 16 + quad * 4 + r;
                int col = n0 + wn + j * 16 + lr;
                float v = acc[i][j][r] + res[(size_t)row * N + col];
                if (outF) outF[(size_t)row * N + col] = v;
                if (outB) outB[(size_t)row * N + col] = f2bf(v);
            }
}

// ------------- V transpose: VT[bh][d][s] -------------
__global__ __launch_bounds__(256) void vtrans(
    const unsigned short* __restrict__ qkv, unsigned short* __restrict__ VT) {
    __shared__ unsigned short t[32][33];
    int bh = blockIdx.z, b = bh >> 4, h = bh & 15;
    int s0 = blockIdx.x * 32, d0 = blockIdx.y * 32;
    int tx = threadIdx.x & 31, ty = threadIdx.x >> 5;
    for (int i = ty; i < 32; i += 8)
        t[i][tx] = qkv[(size_t)(b * 1024 + s0 + i) * 3072 + 2048 + h * 64 + d0 + tx];
    __syncthreads();
    for (int i = ty; i < 32; i += 8)
        VT[((size_t)bh * 64 + d0 + i) * 1024 + s0 + tx] = t[tx][i];
}

// ------------- Flash attention: 512 blocks, one 64-row q-block each -------------
// qblk = bh<16 ? x : 15-x  -> loads 1..16 mixed through dispatch order; greedy
// block scheduler + 2 blocks/CU (2 waves/SIMD) overlap the staging drains.
__global__ __launch_bounds__(256) void attn_kernel(
    const unsigned short* __restrict__ qkv,  // [2048][3072]
    const unsigned short* __restrict__ VT,   // [32][64][1024]
    unsigned short* __restrict__ O) {        // [2048][1024]
    __shared__ __align__(16) unsigned short Ks[2][64 * 32];  // [dhalf][s][d32]
    __shared__ __align__(16) unsigned short Vs[2][64 * 32];  // [shalf][d][s32]
    __shared__ __align__(16) unsigned short pl[4][16 * 72];
    const int tid = threadIdx.x;
    const int w = tid >> 6, lane = tid & 63;
    const int lr = lane & 15, quad = lane >> 4;
    const int bh = blockIdx.y, b = bh >> 4, h = bh & 15;
    const int qblk = (bh < 16) ? blockIdx.x : (15 - blockIdx.x);
    const int qb = qblk * 64 + w * 16;
    const int srow = w * 16 + (lane >> 2);
    const int skof = (lane & 3) * 8;
    const float LOG2E = 1.44269504f;

    const size_t rowQ = (size_t)(b * 1024 + qb + lr) * 3072 + h * 64;
    bf16x8 aq0 = *(const bf16x8*)&qkv[rowQ + quad * 8];
    bf16x8 aq1 = *(const bf16x8*)&qkv[rowQ + 32 + quad * 8];

    float m_i[4], l_i[4];
    f32x4 oacc[4] = {};
    #pragma unroll
    for (int r = 0; r < 4; r++) { m_i[r] = -1e30f; l_i[r] = 0.f; }

    const int nkt = qblk + 1;  // k-tiles of 64
    for (int kt64 = 0; kt64 < nkt; kt64++) {
        const int kt = kt64 << 6;
        __syncthreads();  // prev step's frag reads done
        const size_t gK = (size_t)(b * 1024 + kt + srow) * 3072 + 1024 + h * 64;
        lds_stage16(qkv + gK + skof,      (char*)Ks[0] + w * 1024);
        lds_stage16(qkv + gK + 32 + skof, (char*)Ks[1] + w * 1024);
        const size_t gV = ((size_t)bh * 64 + srow) * 1024 + kt;
        lds_stage16(VT + gV + skof,       (char*)Vs[0] + w * 1024);
        lds_stage16(VT + gV + 32 + skof,  (char*)Vs[1] + w * 1024);
        __syncthreads();  // drains vmcnt(0)

        // QK^T: 16 q-rows x 64 k-cols
        f32x4 s[4] = {};
        #pragma unroll
        for (int nh = 0; nh < 4; nh++) {
            bf16x8 kb0 = *(const bf16x8*)&Ks[0][(nh * 16 + lr) * 32 + quad * 8];
            bf16x8 kb1 = *(const bf16x8*)&Ks[1][(nh * 16 + lr) * 32 + quad * 8];
            s[nh] = mfma16(aq0, kb0, s[nh]);
            s[nh] = mfma16(aq1, kb1, s[nh]);
        }
        float mx[4];
        if (kt + 64 > qb) {  // diagonal tile: causal mask
            #pragma unroll
            for (int r = 0; r < 4; r++) {
                int qrow = qb + quad * 4 + r;
                #pragma unroll
                for (int nh = 0; nh < 4; nh++) {
                    int kcol = kt + nh * 16 + lr;
                    s[nh][r] = (kcol <= qrow) ? s[nh][r] : -1e30f;
                }
            }
        }
        #pragma unroll
        for (int r = 0; r < 4; r++) {
            mx[r] = fmaxf(fmaxf(s[0][r], s[1][r]), fmaxf(s[2][r], s[3][r]));
            RORMAX(mx[r], 0x121) RORMAX(mx[r], 0x122)
            RORMAX(mx[r], 0x124) RORMAX(mx[r], 0x128)
        }
        float al[4];
        #pragma unroll
        for (int r = 0; r < 4; r++) {
            float mnew = fmaxf(m_i[r], mx[r]);
            al[r] = exp2f((m_i[r] - mnew) * LOG2E);
            m_i[r] = mnew;
            float lsum = 0.f;
            #pragma unroll
            for (int nh = 0; nh < 4; nh++) {
                float p = exp2f((s[nh][r] - mnew) * LOG2E);
                s[nh][r] = p;
                lsum += p;
            }
            l_i[r] = l_i[r] * al[r] + lsum;  // lane-local partial
        }
        #pragma unroll
        for (int dt = 0; dt < 4; dt++)
            #pragma unroll
            for (int r = 0; r < 4; r++) oacc[dt][r] *= al[r];
        // P: C-layout -> LDS -> A-layout (wave-internal)
        #pragma unroll
        for (int nh = 0; nh < 4; nh++)
            #pragma unroll
            for (int r = 0; r < 4; r++)
                pl[w][(quad * 4 + r) * 72 + nh * 16 + lr] = f2bf(s[nh][r]);
        bf16x8 ap0 = *(const bf16x8*)&pl[w][lr * 72 + quad * 8];
        bf16x8 ap1 = *(const bf16x8*)&pl[w][lr * 72 + 32 + quad * 8];
        #pragma unroll
        for (int dt = 0; dt < 4; dt++) {
            bf16x8 vb0 = *(const bf16x8*)&Vs[0][(dt * 16 + lr) * 32 + quad * 8];
            bf16x8 vb1 = *(const bf16x8*)&Vs[1][(dt * 16 + lr) * 32 + quad * 8];
            oacc[dt] = mfma16(ap0, vb0, oacc[dt]);
            oacc[dt] = mfma16(ap1, vb1, oacc[dt]);
        }
    }
    // cross-lane finish of l (16 col-lanes per row group)
    #pragma unroll
    for (int r = 0; r < 4; r++) {
        RORADD(l_i[r], 0x121) RORADD(l_i[r], 0x122)
        RORADD(l_i[r], 0x124) RORADD(l_i[r], 0x128)
    }
    #pragma unroll
    for (int dt = 0; dt < 4; dt++)
        #pragma unroll
        for (int r = 0; r < 4; r++) {
            int row = b * 1024 + qb + quad * 4 + r;
            int col = h * 64 + dt * 16 + lr;
            O[(size_t)row * 1024 + col] = f2bf(oacc[dt][r] / l_i[r]);
        }
}

extern "C" void kernel_launch(void* const* d_in, const int* in_sizes, int n_in,
                              void* d_out, int out_size, void* d_ws, size_t ws_size,
                              hipStream_t stream) {
    const float* x     = (const float*)d_in[0];
    const float* Wqkv  = (const float*)d_in[1];
    const float* Aqkv  = (const float*)d_in[2];
    const float* Bqkv  = (const float*)d_in[3];
    const float* Wproj = (const float*)d_in[4];
    const float* Aproj = (const float*)d_in[5];
    const float* Bproj = (const float*)d_in[6];
    float* out = (float*)d_out;

    char* ws = (char*)d_ws;
    float* h_f32 = (float*)ws;                    ws += (size_t)2048 * 1024 * 4;
    unsigned short* h_bf   = (unsigned short*)ws; ws += (size_t)2048 * 1024 * 2;
    unsigned short* qkv_bf = (unsigned short*)ws; ws += (size_t)2048 * 3072 * 2;
    unsigned short* VT     = (unsigned short*)ws; ws += (size_t)32 * 64 * 1024 * 2;
    unsigned short* O_bf   = (unsigned short*)ws; ws += (size_t)2048 * 1024 * 2;
    unsigned short* WqT8   = (unsigned short*)ws; ws += (size_t)8 * 3072 * 1024 * 2;
    unsigned short* WpT8   = (unsigned short*)ws; ws += (size_t)8 * 1024 * 1024 * 2;

    convert_x<<<2048, 256, 0, stream>>>((const float4*)x, (float4*)h_f32,
                                        (ushort4*)h_bf, 2048 * 1024 / 4);
    // all layers' LoRA merges up front (independent of activations)
    merge_T<<<dim3(24, 32, 8), 256, 0, stream>>>(Wqkv, Aqkv, Bqkv, WqT8, 3072);
    merge_T<<<dim3(8, 32, 8), 256, 0, stream>>>(Wproj, Aproj, Bproj, WpT8, 1024);

    for (int l = 0; l < 8; l++) {
        const unsigned short* WqT = WqT8 + (size_t)l * 3072 * 1024;
        const unsigned short* WpT = WpT8 + (size_t)l * 1024 * 1024;
        // qkv GEMM: Q columns pre-scaled by 1/8
        gemm_bf16_128<<<dim3(24, 16), 256, 0, stream>>>(h_bf, WqT, qkv_bf,
                                                        2048, 3072, 1024, 1);
        vtrans<<<dim3(32, 2, 32), 256, 0, stream>>>(qkv_bf, VT);
        attn_kernel<<<dim3(16, 32), 256, 0, stream>>>(qkv_bf, VT, O_bf);
        float* outF = (l == 7) ? out : h_f32;
        gemm_bf16_64<<<dim3(16, 32), 256, 0, stream>>>(O_bf, WpT, h_f32, outF,
                                                       h_bf, 2048, 1024, 1024);
    }
}

// Round 2
// 791.560 us; speedup vs baseline: 1.0239x; 1.0174x over previous
//
#include <hip/hip_runtime.h>
#include <hip/hip_bf16.h>

// LoRA transformer: L=8, D=1024, H=16, HD=64, R=16, B=2, S=1024.
// bf16 MFMA everywhere, fp32 residual stream.
// R7: attn -> 512 blocks; merge_T batched over all 8 layers.
// R8: merge_T bv hoist attempt -> compiler rematerialized (VGPR 40), ~no gain.
// R9: merge_T latency fix: A tile staged in LDS (coalesced, 1 float4/thread),
// W rows preloaded to regs before the barrier, bv loads independent. Loads
// per thread 36 -> ~21, all issued in one MLP window instead of serialized
// chains.

typedef unsigned short ushort_t;
typedef __attribute__((ext_vector_type(8))) short bf16x8;
typedef __attribute__((ext_vector_type(4))) float f32x4;

__device__ __forceinline__ unsigned short f2bf(float f) {
    union { float f; unsigned int u; } x; x.f = f;
    unsigned int r = x.u + 0x7fffu + ((x.u >> 16) & 1u);  // RNE
    return (unsigned short)(r >> 16);
}

__device__ __forceinline__ f32x4 mfma16(bf16x8 a, bf16x8 b, f32x4 c) {
    return __builtin_amdgcn_mfma_f32_16x16x32_bf16(a, b, c, 0, 0, 0);
}

typedef const __attribute__((address_space(1))) unsigned int* gas_ptr;
typedef __attribute__((address_space(3))) unsigned int* las_ptr;
// async global->LDS, 16B/lane; LDS dest = wave-uniform base + lane*16 (m104/m108)
__device__ __forceinline__ void lds_stage16(const void* g, void* l) {
    __builtin_amdgcn_global_load_lds((gas_ptr)(unsigned long long)g,
                                     (las_ptr)(unsigned int)(unsigned long long)l,
                                     16, 0, 0);
}

// DPP 16-lane row reductions (row_ror:S = 0x120+S)
#define RORMAX(x, C)                                                           \
    x = fmaxf(x, __int_as_float(__builtin_amdgcn_mov_dpp(                      \
                     __float_as_int(x), C, 0xf, 0xf, false)));
#define RORADD(x, C)                                                           \
    x += __int_as_float(__builtin_amdgcn_mov_dpp(                              \
        __float_as_int(x), C, 0xf, 0xf, false));

// ---------------- x -> (h_f32 copy, h_bf16) ----------------
__global__ __launch_bounds__(256) void convert_x(
    const float4* __restrict__ in, float4* __restrict__ outF,
    ushort4* __restrict__ outB, int n4) {
    int i = blockIdx.x * 256 + threadIdx.x;
    if (i < n4) {
        float4 v = in[i];
        outF[i] = v;
        ushort4 o;
        o.x = f2bf(v.x); o.y = f2bf(v.y); o.z = f2bf(v.z); o.w = f2bf(v.w);
        outB[i] = o;
    }
}

// ------------- LoRA merge + transpose, batched over layers (z) -------------
// WT[z][n][k] = bf16(W[z][k][n] + A[z][k][:] . B[z][:][n])
__global__ __launch_bounds__(256) void merge_T(
    const float* __restrict__ W, const float* __restrict__ A,
    const float* __restrict__ Bm, unsigned short* __restrict__ WT, int N) {
    __shared__ float t[32][132];
    __shared__ float Asl[32][17];  // A tile (32 rows x 16), +1 pad
    const int z = blockIdx.z;
    W  += (size_t)z * 1024 * N;
    A  += (size_t)z * 1024 * 16;
    Bm += (size_t)z * 16 * N;
    WT += (size_t)z * N * 1024;
    int j0 = blockIdx.x * 128, i0 = blockIdx.y * 32;
    int tx = threadIdx.x & 31, ty = threadIdx.x >> 5;  // 32 x 8

    // Stage A tile cooperatively: 512 floats, 128 threads x float4, coalesced.
    if (threadIdx.x < 128) {
        int r = threadIdx.x >> 2, c4 = (threadIdx.x & 3) * 4;
        float4 a = *(const float4*)&A[(size_t)(i0 + r) * 16 + c4];
        Asl[r][c4 + 0] = a.x; Asl[r][c4 + 1] = a.y;
        Asl[r][c4 + 2] = a.z; Asl[r][c4 + 3] = a.w;
    }
    // Independent global loads, all issued before any use: 16 B cols + 4 W rows.
    float4 bv[16];
    #pragma unroll
    for (int r = 0; r < 16; r++)
        bv[r] = *(const float4*)&Bm[(size_t)r * N + j0 + tx * 4];
    float4 wv[4];
    #pragma unroll
    for (int ii0 = 0; ii0 < 4; ii0++)
        wv[ii0] = *(const float4*)&W[(size_t)(i0 + ty + ii0 * 8) * N + j0 + tx * 4];
    __syncthreads();  // A tile ready (also covers the load latency window)

    #pragma unroll
    for (int ii0 = 0; ii0 < 4; ii0++) {
        int ii = ty + ii0 * 8;
        float4 acc = wv[ii0];
        #pragma unroll
        for (int r = 0; r < 16; r++) {
            float a = Asl[ii][r];  // wave-uniform broadcast read
            acc.x += a * bv[r].x; acc.y += a * bv[r].y;
            acc.z += a * bv[r].z; acc.w += a * bv[r].w;
        }
        *(float4*)&t[ii][tx * 4] = acc;
    }
    __syncthreads();
    int jj = threadIdx.x >> 1, half = threadIdx.x & 1;
    bf16x8 o0, o1;
    #pragma unroll
    for (int c = 0; c < 8; c++) o0[c] = (short)f2bf(t[half * 16 + c][jj]);
    #pragma unroll
    for (int c = 0; c < 8; c++) o1[c] = (short)f2bf(t[half * 16 + 8 + c][jj]);
    unsigned short* dst = &WT[(size_t)(j0 + jj) * 1024 + i0 + half * 16];
    *(bf16x8*)dst = o0;
    *(bf16x8*)(dst + 8) = o1;
}

// ------------- GEMM 128x128, BK=64 (two m97-shape sub-buffers/barrier) -------------
__global__ __launch_bounds__(256) void gemm_bf16_128(
    const unsigned short* __restrict__ A,   // [M][K]
    const unsigned short* __restrict__ BT,  // [N][K]
    unsigned short* __restrict__ outB,      // bf16 out
    int M, int N, int K, int scaleq) {
    __shared__ __align__(16) unsigned short As[2][128 * 32];
    __shared__ __align__(16) unsigned short Bs[2][128 * 32];
    const int tid = threadIdx.x;
    const int m0 = blockIdx.y * 128, n0 = blockIdx.x * 128;
    const int w = tid >> 6, lane = tid & 63;
    const int wm = (w >> 1) * 64, wn = (w & 1) * 64;
    const int lr = lane & 15, quad = lane >> 4;
    const int srow = w * 16 + (lane >> 2);
    const int skof = (lane & 3) * 8;

    f32x4 acc[4][4] = {};

    for (int k0 = 0; k0 < K; k0 += 64) {
        __syncthreads();
        #pragma unroll
        for (int h = 0; h < 2; h++) {
            lds_stage16(A  + (size_t)(m0 + srow)      * K + k0 + h * 32 + skof,
                        (char*)As[h] + w * 1024);
            lds_stage16(A  + (size_t)(m0 + 64 + srow) * K + k0 + h * 32 + skof,
                        (char*)As[h] + 4096 + w * 1024);
            lds_stage16(BT + (size_t)(n0 + srow)      * K + k0 + h * 32 + skof,
                        (char*)Bs[h] + w * 1024);
            lds_stage16(BT + (size_t)(n0 + 64 + srow) * K + k0 + h * 32 + skof,
                        (char*)Bs[h] + 4096 + w * 1024);
        }
        __syncthreads();

        #pragma unroll
        for (int h = 0; h < 2; h++) {
            bf16x8 af[4], bfr[4];
            #pragma unroll
            for (int i = 0; i < 4; i++) {
                af[i]  = *(const bf16x8*)&As[h][(wm + i * 16 + lr) * 32 + quad * 8];
                bfr[i] = *(const bf16x8*)&Bs[h][(wn + i * 16 + lr) * 32 + quad * 8];
            }
            #pragma unroll
            for (int i = 0; i < 4; i++)
                #pragma unroll
                for (int j = 0; j < 4; j++)
                    acc[i][j] = mfma16(af[i], bfr[j], acc[i][j]);
        }
    }
    #pragma unroll
    for (int i = 0; i < 4; i++)
        #pragma unroll
        for (int j = 0; j < 4; j++)
            #pragma unroll
            for (int r = 0; r < 4; r++) {
                int row = m0 + wm + i * 16 + quad * 4 + r;
                int col = n0 + wn + j * 16 + lr;
                float v = acc[i][j][r];
                if (scaleq && col < 1024) v *= 0.125f;
                outB[(size_t)row * N + col] = f2bf(v);
            }
}

// ------------- GEMM 64x64, BK=64 (proj: 512 blocks, 2/CU) + residual -------------
__global__ __launch_bounds__(256) void gemm_bf16_64(
    const unsigned short* __restrict__ A,   // [M][K]
    const unsigned short* __restrict__ BT,  // [N][K]
    const float* __restrict__ res,          // [M][N] residual
    float* __restrict__ outF,               // fp32 out
    unsigned short* __restrict__ outB,      // bf16 out
    int M, int N, int K) {
    __shared__ __align__(16) unsigned short As[2][64 * 32];
    __shared__ __align__(16) unsigned short Bs[2][64 * 32];
    const int tid = threadIdx.x;
    const int m0 = blockIdx.y * 64, n0 = blockIdx.x * 64;
    const int w = tid >> 6, lane = tid & 63;
    const int wm = (w >> 1) * 32, wn = (w & 1) * 32;
    const int lr = lane & 15, quad = lane >> 4;
    const int srow = w * 16 + (lane >> 2);
    const int skof = (lane & 3) * 8;

    f32x4 acc[2][2] = {};

    for (int k0 = 0; k0 < K; k0 += 64) {
        __syncthreads();
        #pragma unroll
        for (int h = 0; h < 2; h++) {
            lds_stage16(A  + (size_t)(m0 + srow) * K + k0 + h * 32 + skof,
                        (char*)As[h] + w * 1024);
            lds_stage16(BT + (size_t)(n0 + srow) * K + k0 + h * 32 + skof,
                        (char*)Bs[h] + w * 1024);
        }
        __syncthreads();

        #pragma unroll
        for (int h = 0; h < 2; h++) {
            bf16x8 af[2], bfr[2];
            #pragma unroll
            for (int i = 0; i < 2; i++) {
                af[i]  = *(const bf16x8*)&As[h][(wm + i * 16 + lr) * 32 + quad * 8];
                bfr[i] = *(const bf16x8*)&Bs[h][(wn + i * 16 + lr) * 32 + quad * 8];
            }
            #pragma unroll
            for (int i = 0; i < 2; i++)
                #pragma unroll
                for (int j = 0; j < 2; j++)
                    acc[i][j] = mfma16(af[i], bfr[j], acc[i][j]);
        }
    }
    #pragma unroll
    for (int i = 0; i < 2; i++)
        #pragma unroll
        for (int j = 0; j < 2; j++)
            #pragma unroll
            for (int r = 0; r < 4; r++) {
                int row = m0 + wm + i * 16 + quad * 4 + r;
                int col = n0 + wn + j * 16 + lr;
                float v = acc[i][j][r] + res[(size_t)row * N + col];
                if (outF) outF[(size_t)row * N + col] = v;
                if (outB) outB[(size_t)row * N + col] = f2bf(v);
            }
}

// ------------- V transpose: VT[bh][d][s] -------------
__global__ __launch_bounds__(256) void vtrans(
    const unsigned short* __restrict__ qkv, unsigned short* __restrict__ VT) {
    __shared__ unsigned short t[32][33];
    int bh = blockIdx.z, b = bh >> 4, h = bh & 15;
    int s0 = blockIdx.x * 32, d0 = blockIdx.y * 32;
    int tx = threadIdx.x & 31, ty = threadIdx.x >> 5;
    for (int i = ty; i < 32; i += 8)
        t[i][tx] = qkv[(size_t)(b * 1024 + s0 + i) * 3072 + 2048 + h * 64 + d0 + tx];
    __syncthreads();
    for (int i = ty; i < 32; i += 8)
        VT[((size_t)bh * 64 + d0 + i) * 1024 + s0 + tx] = t[tx][i];
}

// ------------- Flash attention: 512 blocks, one 64-row q-block each -------------
// qblk = bh<16 ? x : 15-x  -> loads 1..16 mixed through dispatch order; greedy
// block scheduler + 2 blocks/CU (2 waves/SIMD) overlap the staging drains.
__global__ __launch_bounds__(256) void attn_kernel(
    const unsigned short* __restrict__ qkv,  // [2048][3072]
    const unsigned short* __restrict__ VT,   // [32][64][1024]
    unsigned short* __restrict__ O) {        // [2048][1024]
    __shared__ __align__(16) unsigned short Ks[2][64 * 32];  // [dhalf][s][d32]
    __shared__ __align__(16) unsigned short Vs[2][64 * 32];  // [shalf][d][s32]
    __shared__ __align__(16) unsigned short pl[4][16 * 72];
    const int tid = threadIdx.x;
    const int w = tid >> 6, lane = tid & 63;
    const int lr = lane & 15, quad = lane >> 4;
    const int bh = blockIdx.y, b = bh >> 4, h = bh & 15;
    const int qblk = (bh < 16) ? blockIdx.x : (15 - blockIdx.x);
    const int qb = qblk * 64 + w * 16;
    const int srow = w * 16 + (lane >> 2);
    const int skof = (lane & 3) * 8;
    const float LOG2E = 1.44269504f;

    const size_t rowQ = (size_t)(b * 1024 + qb + lr) * 3072 + h * 64;
    bf16x8 aq0 = *(const bf16x8*)&qkv[rowQ + quad * 8];
    bf16x8 aq1 = *(const bf16x8*)&qkv[rowQ + 32 + quad * 8];

    float m_i[4], l_i[4];
    f32x4 oacc[4] = {};
    #pragma unroll
    for (int r = 0; r < 4; r++) { m_i[r] = -1e30f; l_i[r] = 0.f; }

    const int nkt = qblk + 1;  // k-tiles of 64
    for (int kt64 = 0; kt64 < nkt; kt64++) {
        const int kt = kt64 << 6;
        __syncthreads();  // prev step's frag reads done
        const size_t gK = (size_t)(b * 1024 + kt + srow) * 3072 + 1024 + h * 64;
        lds_stage16(qkv + gK + skof,      (char*)Ks[0] + w * 1024);
        lds_stage16(qkv + gK + 32 + skof, (char*)Ks[1] + w * 1024);
        const size_t gV = ((size_t)bh * 64 + srow) * 1024 + kt;
        lds_stage16(VT + gV + skof,       (char*)Vs[0] + w * 1024);
        lds_stage16(VT + gV + 32 + skof,  (char*)Vs[1] + w * 1024);
        __syncthreads();  // drains vmcnt(0)

        // QK^T: 16 q-rows x 64 k-cols
        f32x4 s[4] = {};
        #pragma unroll
        for (int nh = 0; nh < 4; nh++) {
            bf16x8 kb0 = *(const bf16x8*)&Ks[0][(nh * 16 + lr) * 32 + quad * 8];
            bf16x8 kb1 = *(const bf16x8*)&Ks[1][(nh * 16 + lr) * 32 + quad * 8];
            s[nh] = mfma16(aq0, kb0, s[nh]);
            s[nh] = mfma16(aq1, kb1, s[nh]);
        }
        float mx[4];
        if (kt + 64 > qb) {  // diagonal tile: causal mask
            #pragma unroll
            for (int r = 0; r < 4; r++) {
                int qrow = qb + quad * 4 + r;
                #pragma unroll
                for (int nh = 0; nh < 4; nh++) {
                    int kcol = kt + nh * 16 + lr;
                    s[nh][r] = (kcol <= qrow) ? s[nh][r] : -1e30f;
                }
            }
        }
        #pragma unroll
        for (int r = 0; r < 4; r++) {
            mx[r] = fmaxf(fmaxf(s[0][r], s[1][r]), fmaxf(s[2][r], s[3][r]));
            RORMAX(mx[r], 0x121) RORMAX(mx[r], 0x122)
            RORMAX(mx[r], 0x124) RORMAX(mx[r], 0x128)
        }
        float al[4];
        #pragma unroll
        for (int r = 0; r < 4; r++) {
            float mnew = fmaxf(m_i[r], mx[r]);
            al[r] = exp2f((m_i[r] - mnew) * LOG2E);
            m_i[r] = mnew;
            float lsum = 0.f;
            #pragma unroll
            for (int nh = 0; nh < 4; nh++) {
                float p = exp2f((s[nh][r] - mnew) * LOG2E);
                s[nh][r] = p;
                lsum += p;
            }
            l_i[r] = l_i[r] * al[r] + lsum;  // lane-local partial
        }
        #pragma unroll
        for (int dt = 0; dt < 4; dt++)
            #pragma unroll
            for (int r = 0; r < 4; r++) oacc[dt][r] *= al[r];
        // P: C-layout -> LDS -> A-layout (wave-internal)
        #pragma unroll
        for (int nh = 0; nh < 4; nh++)
            #pragma unroll
            for (int r = 0; r < 4; r++)
                pl[w][(quad * 4 + r) * 72 + nh * 16 + lr] = f2bf(s[nh][r]);
        bf16x8 ap0 = *(const bf16x8*)&pl[w][lr * 72 + quad * 8];
        bf16x8 ap1 = *(const bf16x8*)&pl[w][lr * 72 + 32 + quad * 8];
        #pragma unroll
        for (int dt = 0; dt < 4; dt++) {
            bf16x8 vb0 = *(const bf16x8*)&Vs[0][(dt * 16 + lr) * 32 + quad * 8];
            bf16x8 vb1 = *(const bf16x8*)&Vs[1][(dt * 16 + lr) * 32 + quad * 8];
            oacc[dt] = mfma16(ap0, vb0, oacc[dt]);
            oacc[dt] = mfma16(ap1, vb1, oacc[dt]);
        }
    }
    // cross-lane finish of l (16 col-lanes per row group)
    #pragma unroll
    for (int r = 0; r < 4; r++) {
        RORADD(l_i[r], 0x121) RORADD(l_i[r], 0x122)
        RORADD(l_i[r], 0x124) RORADD(l_i[r], 0x128)
    }
    #pragma unroll
    for (int dt = 0; dt < 4; dt++)
        #pragma unroll
        for (int r = 0; r < 4; r++) {
            int row = b * 1024 + qb + quad * 4 + r;
            int col = h * 64 + dt * 16 + lr;
            O[(size_t)row * 1024 + col] = f2bf(oacc[dt][r] / l_i[r]);
        }
}

extern "C" void kernel_launch(void* const* d_in, const int* in_sizes, int n_in,
                              void* d_out, int out_size, void* d_ws, size_t ws_size,
                              hipStream_t stream) {
    const float* x     = (const float*)d_in[0];
    const float* Wqkv  = (const float*)d_in[1];
    const float* Aqkv  = (const float*)d_in[2];
    const float* Bqkv  = (const float*)d_in[3];
    const float* Wproj = (const float*)d_in[4];
    const float* Aproj = (const float*)d_in[5];
    const float* Bproj = (const float*)d_in[6];
    float* out = (float*)d_out;

    char* ws = (char*)d_ws;
    float* h_f32 = (float*)ws;                    ws += (size_t)2048 * 1024 * 4;
    unsigned short* h_bf   = (unsigned short*)ws; ws += (size_t)2048 * 1024 * 2;
    unsigned short* qkv_bf = (unsigned short*)ws; ws += (size_t)2048 * 3072 * 2;
    unsigned short* VT     = (unsigned short*)ws; ws += (size_t)32 * 64 * 1024 * 2;
    unsigned short* O_bf   = (unsigned short*)ws; ws += (size_t)2048 * 1024 * 2;
    unsigned short* WqT8   = (unsigned short*)ws; ws += (size_t)8 * 3072 * 1024 * 2;
    unsigned short* WpT8   = (unsigned short*)ws; ws += (size_t)8 * 1024 * 1024 * 2;

    convert_x<<<2048, 256, 0, stream>>>((const float4*)x, (float4*)h_f32,
                                        (ushort4*)h_bf, 2048 * 1024 / 4);
    // all layers' LoRA merges up front (independent of activations)
    merge_T<<<dim3(24, 32, 8), 256, 0, stream>>>(Wqkv, Aqkv, Bqkv, WqT8, 3072);
    merge_T<<<dim3(8, 32, 8), 256, 0, stream>>>(Wproj, Aproj, Bproj, WpT8, 1024);

    for (int l = 0; l < 8; l++) {
        const unsigned short* WqT = WqT8 + (size_t)l * 3072 * 1024;
        const unsigned short* WpT = WpT8 + (size_t)l * 1024 * 1024;
        // qkv GEMM: Q columns pre-scaled by 1/8
        gemm_bf16_128<<<dim3(24, 16), 256, 0, stream>>>(h_bf, WqT, qkv_bf,
                                                        2048, 3072, 1024, 1);
        vtrans<<<dim3(32, 2, 32), 256, 0, stream>>>(qkv_bf, VT);
        attn_kernel<<<dim3(16, 32), 256, 0, stream>>>(qkv_bf, VT, O_bf);
        float* outF = (l == 7) ? out : h_f32;
        gemm_bf16_64<<<dim3(16, 32), 256, 0, stream>>>(O_bf, WpT, h_f32, outF,
                                                       h_bf, 2048, 1024, 1024);
    }
}

// Round 3
// 742.299 us; speedup vs baseline: 1.0918x; 1.0664x over previous
//
#include <hip/hip_runtime.h>
#include <hip/hip_bf16.h>

// LoRA transformer: L=8, D=1024, H=16, HD=64, R=16, B=2, S=1024.
// bf16 MFMA everywhere, fp32 residual stream.
// R7: attn -> 512 blocks; merge_T batched over all 8 layers.
// R9: merge_T latency fix (A tile via LDS, independent bv/wv loads).
// R10: attn + gemm64 -> double-buffered LDS, ONE barrier per tile (stage(t+1)
// issued after the barrier, compute tile t, next barrier's vmcnt(0) drain is
// exactly where t+1 is needed). merge_T qkv+proj combined into one dispatch.

typedef unsigned short ushort_t;
typedef __attribute__((ext_vector_type(8))) short bf16x8;
typedef __attribute__((ext_vector_type(4))) float f32x4;

__device__ __forceinline__ unsigned short f2bf(float f) {
    union { float f; unsigned int u; } x; x.f = f;
    unsigned int r = x.u + 0x7fffu + ((x.u >> 16) & 1u);  // RNE
    return (unsigned short)(r >> 16);
}

__device__ __forceinline__ f32x4 mfma16(bf16x8 a, bf16x8 b, f32x4 c) {
    return __builtin_amdgcn_mfma_f32_16x16x32_bf16(a, b, c, 0, 0, 0);
}

typedef const __attribute__((address_space(1))) unsigned int* gas_ptr;
typedef __attribute__((address_space(3))) unsigned int* las_ptr;
// async global->LDS, 16B/lane; LDS dest = wave-uniform base + lane*16 (m104/m108)
__device__ __forceinline__ void lds_stage16(const void* g, void* l) {
    __builtin_amdgcn_global_load_lds((gas_ptr)(unsigned long long)g,
                                     (las_ptr)(unsigned int)(unsigned long long)l,
                                     16, 0, 0);
}

// DPP 16-lane row reductions (row_ror:S = 0x120+S)
#define RORMAX(x, C)                                                           \
    x = fmaxf(x, __int_as_float(__builtin_amdgcn_mov_dpp(                      \
                     __float_as_int(x), C, 0xf, 0xf, false)));
#define RORADD(x, C)                                                           \
    x += __int_as_float(__builtin_amdgcn_mov_dpp(                              \
        __float_as_int(x), C, 0xf, 0xf, false));

// ---------------- x -> (h_f32 copy, h_bf16) ----------------
__global__ __launch_bounds__(256) void convert_x(
    const float4* __restrict__ in, float4* __restrict__ outF,
    ushort4* __restrict__ outB, int n4) {
    int i = blockIdx.x * 256 + threadIdx.x;
    if (i < n4) {
        float4 v = in[i];
        outF[i] = v;
        ushort4 o;
        o.x = f2bf(v.x); o.y = f2bf(v.y); o.z = f2bf(v.z); o.w = f2bf(v.w);
        outB[i] = o;
    }
}

// ------------- LoRA merge + transpose, qkv + proj in ONE dispatch -------------
// blocks 0..6143: qkv (24x32x8); blocks 6144..8191: proj (8x32x8)
// WT[z][n][k] = bf16(W[z][k][n] + A[z][k][:] . B[z][:][n])
__global__ __launch_bounds__(256) void merge_T2(
    const float* __restrict__ Wq, const float* __restrict__ Aq,
    const float* __restrict__ Bq, unsigned short* __restrict__ WTq,
    const float* __restrict__ Wp, const float* __restrict__ Ap,
    const float* __restrict__ Bp, unsigned short* __restrict__ WTp) {
    __shared__ float t[32][132];
    __shared__ float Asl[32][17];  // A tile (32 rows x 16), +1 pad
    int bid = blockIdx.x;
    const float *W, *A, *Bm;
    unsigned short* WT;
    int N, bx, by, bz;
    if (bid < 6144) {
        N = 3072; bx = bid % 24; int u = bid / 24; by = u & 31; bz = u >> 5;
        W = Wq; A = Aq; Bm = Bq; WT = WTq;
    } else {
        bid -= 6144;
        N = 1024; bx = bid & 7; int u = bid >> 3; by = u & 31; bz = u >> 5;
        W = Wp; A = Ap; Bm = Bp; WT = WTp;
    }
    W  += (size_t)bz * 1024 * N;
    A  += (size_t)bz * 1024 * 16;
    Bm += (size_t)bz * 16 * N;
    WT += (size_t)bz * N * 1024;
    int j0 = bx * 128, i0 = by * 32;
    int tx = threadIdx.x & 31, ty = threadIdx.x >> 5;  // 32 x 8

    // Stage A tile cooperatively: 512 floats, 128 threads x float4, coalesced.
    if (threadIdx.x < 128) {
        int r = threadIdx.x >> 2, c4 = (threadIdx.x & 3) * 4;
        float4 a = *(const float4*)&A[(size_t)(i0 + r) * 16 + c4];
        Asl[r][c4 + 0] = a.x; Asl[r][c4 + 1] = a.y;
        Asl[r][c4 + 2] = a.z; Asl[r][c4 + 3] = a.w;
    }
    // Independent global loads, all issued before any use: 16 B cols + 4 W rows.
    float4 bv[16];
    #pragma unroll
    for (int r = 0; r < 16; r++)
        bv[r] = *(const float4*)&Bm[(size_t)r * N + j0 + tx * 4];
    float4 wv[4];
    #pragma unroll
    for (int ii0 = 0; ii0 < 4; ii0++)
        wv[ii0] = *(const float4*)&W[(size_t)(i0 + ty + ii0 * 8) * N + j0 + tx * 4];
    __syncthreads();  // A tile ready (also covers the load latency window)

    #pragma unroll
    for (int ii0 = 0; ii0 < 4; ii0++) {
        int ii = ty + ii0 * 8;
        float4 acc = wv[ii0];
        #pragma unroll
        for (int r = 0; r < 16; r++) {
            float a = Asl[ii][r];  // wave-uniform broadcast read
            acc.x += a * bv[r].x; acc.y += a * bv[r].y;
            acc.z += a * bv[r].z; acc.w += a * bv[r].w;
        }
        *(float4*)&t[ii][tx * 4] = acc;
    }
    __syncthreads();
    int jj = threadIdx.x >> 1, half = threadIdx.x & 1;
    bf16x8 o0, o1;
    #pragma unroll
    for (int c = 0; c < 8; c++) o0[c] = (short)f2bf(t[half * 16 + c][jj]);
    #pragma unroll
    for (int c = 0; c < 8; c++) o1[c] = (short)f2bf(t[half * 16 + 8 + c][jj]);
    unsigned short* dst = &WT[(size_t)(j0 + jj) * 1024 + i0 + half * 16];
    *(bf16x8*)dst = o0;
    *(bf16x8*)(dst + 8) = o1;
}

// ------------- GEMM 128x128, BK=64 (two m97-shape sub-buffers/barrier) -------------
__global__ __launch_bounds__(256) void gemm_bf16_128(
    const unsigned short* __restrict__ A,   // [M][K]
    const unsigned short* __restrict__ BT,  // [N][K]
    unsigned short* __restrict__ outB,      // bf16 out
    int M, int N, int K, int scaleq) {
    __shared__ __align__(16) unsigned short As[2][128 * 32];
    __shared__ __align__(16) unsigned short Bs[2][128 * 32];
    const int tid = threadIdx.x;
    const int m0 = blockIdx.y * 128, n0 = blockIdx.x * 128;
    const int w = tid >> 6, lane = tid & 63;
    const int wm = (w >> 1) * 64, wn = (w & 1) * 64;
    const int lr = lane & 15, quad = lane >> 4;
    const int srow = w * 16 + (lane >> 2);
    const int skof = (lane & 3) * 8;

    f32x4 acc[4][4] = {};

    for (int k0 = 0; k0 < K; k0 += 64) {
        __syncthreads();
        #pragma unroll
        for (int h = 0; h < 2; h++) {
            lds_stage16(A  + (size_t)(m0 + srow)      * K + k0 + h * 32 + skof,
                        (char*)As[h] + w * 1024);
            lds_stage16(A  + (size_t)(m0 + 64 + srow) * K + k0 + h * 32 + skof,
                        (char*)As[h] + 4096 + w * 1024);
            lds_stage16(BT + (size_t)(n0 + srow)      * K + k0 + h * 32 + skof,
                        (char*)Bs[h] + w * 1024);
            lds_stage16(BT + (size_t)(n0 + 64 + srow) * K + k0 + h * 32 + skof,
                        (char*)Bs[h] + 4096 + w * 1024);
        }
        __syncthreads();

        #pragma unroll
        for (int h = 0; h < 2; h++) {
            bf16x8 af[4], bfr[4];
            #pragma unroll
            for (int i = 0; i < 4; i++) {
                af[i]  = *(const bf16x8*)&As[h][(wm + i * 16 + lr) * 32 + quad * 8];
                bfr[i] = *(const bf16x8*)&Bs[h][(wn + i * 16 + lr) * 32 + quad * 8];
            }
            #pragma unroll
            for (int i = 0; i < 4; i++)
                #pragma unroll
                for (int j = 0; j < 4; j++)
                    acc[i][j] = mfma16(af[i], bfr[j], acc[i][j]);
        }
    }
    #pragma unroll
    for (int i = 0; i < 4; i++)
        #pragma unroll
        for (int j = 0; j < 4; j++)
            #pragma unroll
            for (int r = 0; r < 4; r++) {
                int row = m0 + wm + i * 16 + quad * 4 + r;
                int col = n0 + wn + j * 16 + lr;
                float v = acc[i][j][r];
                if (scaleq && col < 1024) v *= 0.125f;
                outB[(size_t)row * N + col] = f2bf(v);
            }
}

// ------------- GEMM 64x64 + residual: dbuf LDS, one barrier/tile -------------
__global__ __launch_bounds__(256) void gemm_bf16_64(
    const unsigned short* __restrict__ A,   // [M][K]
    const unsigned short* __restrict__ BT,  // [N][K]
    const float* __restrict__ res,          // [M][N] residual
    float* __restrict__ outF,               // fp32 out
    unsigned short* __restrict__ outB,      // bf16 out
    int M, int N, int K) {
    __shared__ __align__(16) unsigned short As[2][2][64 * 32];  // [buf][half]
    __shared__ __align__(16) unsigned short Bs[2][2][64 * 32];
    const int tid = threadIdx.x;
    const int m0 = blockIdx.y * 64, n0 = blockIdx.x * 64;
    const int w = tid >> 6, lane = tid & 63;
    const int wm = (w >> 1) * 32, wn = (w & 1) * 32;
    const int lr = lane & 15, quad = lane >> 4;
    const int srow = w * 16 + (lane >> 2);
    const int skof = (lane & 3) * 8;

    f32x4 acc[2][2] = {};

    auto stage = [&](int k0, int buf) {
        #pragma unroll
        for (int h = 0; h < 2; h++) {
            lds_stage16(A  + (size_t)(m0 + srow) * K + k0 + h * 32 + skof,
                        (char*)As[buf][h] + w * 1024);
            lds_stage16(BT + (size_t)(n0 + srow) * K + k0 + h * 32 + skof,
                        (char*)Bs[buf][h] + w * 1024);
        }
    };

    const int nk = K >> 6;
    stage(0, 0);
    for (int t = 0; t < nk; t++) {
        __syncthreads();  // drains stage(t) [vmcnt(0)] + prior reads of buf t&1
        if (t + 1 < nk) stage((t + 1) << 6, (t + 1) & 1);
        const int cur = t & 1;
        #pragma unroll
        for (int h = 0; h < 2; h++) {
            bf16x8 af[2], bfr[2];
            #pragma unroll
            for (int i = 0; i < 2; i++) {
                af[i]  = *(const bf16x8*)&As[cur][h][(wm + i * 16 + lr) * 32 + quad * 8];
                bfr[i] = *(const bf16x8*)&Bs[cur][h][(wn + i * 16 + lr) * 32 + quad * 8];
            }
            #pragma unroll
            for (int i = 0; i < 2; i++)
                #pragma unroll
                for (int j = 0; j < 2; j++)
                    acc[i][j] = mfma16(af[i], bfr[j], acc[i][j]);
        }
    }
    #pragma unroll
    for (int i = 0; i < 2; i++)
        #pragma unroll
        for (int j = 0; j < 2; j++)
            #pragma unroll
            for (int r = 0; r < 4; r++) {
                int row = m0 + wm + i * 16 + quad * 4 + r;
                int col = n0 + wn + j * 16 + lr;
                float v = acc[i][j][r] + res[(size_t)row * N + col];
                if (outF) outF[(size_t)row * N + col] = v;
                if (outB) outB[(size_t)row * N + col] = f2bf(v);
            }
}

// ------------- V transpose: VT[bh][d][s] -------------
__global__ __launch_bounds__(256) void vtrans(
    const unsigned short* __restrict__ qkv, unsigned short* __restrict__ VT) {
    __shared__ unsigned short t[32][33];
    int bh = blockIdx.z, b = bh >> 4, h = bh & 15;
    int s0 = blockIdx.x * 32, d0 = blockIdx.y * 32;
    int tx = threadIdx.x & 31, ty = threadIdx.x >> 5;
    for (int i = ty; i < 32; i += 8)
        t[i][tx] = qkv[(size_t)(b * 1024 + s0 + i) * 3072 + 2048 + h * 64 + d0 + tx];
    __syncthreads();
    for (int i = ty; i < 32; i += 8)
        VT[((size_t)bh * 64 + d0 + i) * 1024 + s0 + tx] = t[tx][i];
}

// ------------- Flash attention: dbuf K/V staging, one barrier/tile -------------
// 512 blocks, one 64-row q-block each; qblk = bh<16 ? x : 15-x.
__global__ __launch_bounds__(256) void attn_kernel(
    const unsigned short* __restrict__ qkv,  // [2048][3072]
    const unsigned short* __restrict__ VT,   // [32][64][1024]
    unsigned short* __restrict__ O) {        // [2048][1024]
    __shared__ __align__(16) unsigned short Ks[2][2][64 * 32];  // [buf][dhalf][s][d32]
    __shared__ __align__(16) unsigned short Vs[2][2][64 * 32];  // [buf][shalf][d][s32]
    __shared__ __align__(16) unsigned short pl[4][16 * 72];
    const int tid = threadIdx.x;
    const int w = tid >> 6, lane = tid & 63;
    const int lr = lane & 15, quad = lane >> 4;
    const int bh = blockIdx.y, b = bh >> 4, h = bh & 15;
    const int qblk = (bh < 16) ? blockIdx.x : (15 - blockIdx.x);
    const int qb = qblk * 64 + w * 16;
    const int srow = w * 16 + (lane >> 2);
    const int skof = (lane & 3) * 8;
    const float LOG2E = 1.44269504f;

    const size_t rowQ = (size_t)(b * 1024 + qb + lr) * 3072 + h * 64;
    bf16x8 aq0 = *(const bf16x8*)&qkv[rowQ + quad * 8];
    bf16x8 aq1 = *(const bf16x8*)&qkv[rowQ + 32 + quad * 8];

    float m_i[4], l_i[4];
    f32x4 oacc[4] = {};
    #pragma unroll
    for (int r = 0; r < 4; r++) { m_i[r] = -1e30f; l_i[r] = 0.f; }

    auto stage = [&](int kt64, int buf) {
        const int kt = kt64 << 6;
        const size_t gK = (size_t)(b * 1024 + kt + srow) * 3072 + 1024 + h * 64;
        lds_stage16(qkv + gK + skof,      (char*)Ks[buf][0] + w * 1024);
        lds_stage16(qkv + gK + 32 + skof, (char*)Ks[buf][1] + w * 1024);
        const size_t gV = ((size_t)bh * 64 + srow) * 1024 + kt;
        lds_stage16(VT + gV + skof,       (char*)Vs[buf][0] + w * 1024);
        lds_stage16(VT + gV + 32 + skof,  (char*)Vs[buf][1] + w * 1024);
    };

    const int nkt = qblk + 1;  // k-tiles of 64
    stage(0, 0);
    for (int kt64 = 0; kt64 < nkt; kt64++) {
        __syncthreads();  // drains stage(kt64); prior reads of next buf done
        if (kt64 + 1 < nkt) stage(kt64 + 1, (kt64 + 1) & 1);
        const int cur = kt64 & 1;
        const int kt = kt64 << 6;

        // QK^T: 16 q-rows x 64 k-cols
        f32x4 s[4] = {};
        #pragma unroll
        for (int nh = 0; nh < 4; nh++) {
            bf16x8 kb0 = *(const bf16x8*)&Ks[cur][0][(nh * 16 + lr) * 32 + quad * 8];
            bf16x8 kb1 = *(const bf16x8*)&Ks[cur][1][(nh * 16 + lr) * 32 + quad * 8];
            s[nh] = mfma16(aq0, kb0, s[nh]);
            s[nh] = mfma16(aq1, kb1, s[nh]);
        }
        float mx[4];
        if (kt + 64 > qb) {  // diagonal tile: causal mask
            #pragma unroll
            for (int r = 0; r < 4; r++) {
                int qrow = qb + quad * 4 + r;
                #pragma unroll
                for (int nh = 0; nh < 4; nh++) {
                    int kcol = kt + nh * 16 + lr;
                    s[nh][r] = (kcol <= qrow) ? s[nh][r] : -1e30f;
                }
            }
        }
        #pragma unroll
        for (int r = 0; r < 4; r++) {
            mx[r] = fmaxf(fmaxf(s[0][r], s[1][r]), fmaxf(s[2][r], s[3][r]));
            RORMAX(mx[r], 0x121) RORMAX(mx[r], 0x122)
            RORMAX(mx[r], 0x124) RORMAX(mx[r], 0x128)
        }
        float al[4];
        #pragma unroll
        for (int r = 0; r < 4; r++) {
            float mnew = fmaxf(m_i[r], mx[r]);
            al[r] = exp2f((m_i[r] - mnew) * LOG2E);
            m_i[r] = mnew;
            float lsum = 0.f;
            #pragma unroll
            for (int nh = 0; nh < 4; nh++) {
                float p = exp2f((s[nh][r] - mnew) * LOG2E);
                s[nh][r] = p;
                lsum += p;
            }
            l_i[r] = l_i[r] * al[r] + lsum;  // lane-local partial
        }
        #pragma unroll
        for (int dt = 0; dt < 4; dt++)
            #pragma unroll
            for (int r = 0; r < 4; r++) oacc[dt][r] *= al[r];
        // P: C-layout -> LDS -> A-layout (wave-internal)
        #pragma unroll
        for (int nh = 0; nh < 4; nh++)
            #pragma unroll
            for (int r = 0; r < 4; r++)
                pl[w][(quad * 4 + r) * 72 + nh * 16 + lr] = f2bf(s[nh][r]);
        bf16x8 ap0 = *(const bf16x8*)&pl[w][lr * 72 + quad * 8];
        bf16x8 ap1 = *(const bf16x8*)&pl[w][lr * 72 + 32 + quad * 8];
        #pragma unroll
        for (int dt = 0; dt < 4; dt++) {
            bf16x8 vb0 = *(const bf16x8*)&Vs[cur][0][(dt * 16 + lr) * 32 + quad * 8];
            bf16x8 vb1 = *(const bf16x8*)&Vs[cur][1][(dt * 16 + lr) * 32 + quad * 8];
            oacc[dt] = mfma16(ap0, vb0, oacc[dt]);
            oacc[dt] = mfma16(ap1, vb1, oacc[dt]);
        }
    }
    // cross-lane finish of l (16 col-lanes per row group)
    #pragma unroll
    for (int r = 0; r < 4; r++) {
        RORADD(l_i[r], 0x121) RORADD(l_i[r], 0x122)
        RORADD(l_i[r], 0x124) RORADD(l_i[r], 0x128)
    }
    #pragma unroll
    for (int dt = 0; dt < 4; dt++)
        #pragma unroll
        for (int r = 0; r < 4; r++) {
            int row = b * 1024 + qb + quad * 4 + r;
            int col = h * 64 + dt * 16 + lr;
            O[(size_t)row * 1024 + col] = f2bf(oacc[dt][r] / l_i[r]);
        }
}

extern "C" void kernel_launch(void* const* d_in, const int* in_sizes, int n_in,
                              void* d_out, int out_size, void* d_ws, size_t ws_size,
                              hipStream_t stream) {
    const float* x     = (const float*)d_in[0];
    const float* Wqkv  = (const float*)d_in[1];
    const float* Aqkv  = (const float*)d_in[2];
    const float* Bqkv  = (const float*)d_in[3];
    const float* Wproj = (const float*)d_in[4];
    const float* Aproj = (const float*)d_in[5];
    const float* Bproj = (const float*)d_in[6];
    float* out = (float*)d_out;

    char* ws = (char*)d_ws;
    float* h_f32 = (float*)ws;                    ws += (size_t)2048 * 1024 * 4;
    unsigned short* h_bf   = (unsigned short*)ws; ws += (size_t)2048 * 1024 * 2;
    unsigned short* qkv_bf = (unsigned short*)ws; ws += (size_t)2048 * 3072 * 2;
    unsigned short* VT     = (unsigned short*)ws; ws += (size_t)32 * 64 * 1024 * 2;
    unsigned short* O_bf   = (unsigned short*)ws; ws += (size_t)2048 * 1024 * 2;
    unsigned short* WqT8   = (unsigned short*)ws; ws += (size_t)8 * 3072 * 1024 * 2;
    unsigned short* WpT8   = (unsigned short*)ws; ws += (size_t)8 * 1024 * 1024 * 2;

    convert_x<<<2048, 256, 0, stream>>>((const float4*)x, (float4*)h_f32,
                                        (ushort4*)h_bf, 2048 * 1024 / 4);
    // all layers' LoRA merges up front (independent of activations), one dispatch
    merge_T2<<<8192, 256, 0, stream>>>(Wqkv, Aqkv, Bqkv, WqT8,
                                       Wproj, Aproj, Bproj, WpT8);

    for (int l = 0; l < 8; l++) {
        const unsigned short* WqT = WqT8 + (size_t)l * 3072 * 1024;
        const unsigned short* WpT = WpT8 + (size_t)l * 1024 * 1024;
        // qkv GEMM: Q columns pre-scaled by 1/8
        gemm_bf16_128<<<dim3(24, 16), 256, 0, stream>>>(h_bf, WqT, qkv_bf,
                                                        2048, 3072, 1024, 1);
        vtrans<<<dim3(32, 2, 32), 256, 0, stream>>>(qkv_bf, VT);
        attn_kernel<<<dim3(16, 32), 256, 0, stream>>>(qkv_bf, VT, O_bf);
        float* outF = (l == 7) ? out : h_f32;
        gemm_bf16_64<<<dim3(16, 32), 256, 0, stream>>>(O_bf, WpT, h_f32, outF,
                                                       h_bf, 2048, 1024, 1024);
    }
}

// Round 4
// 716.991 us; speedup vs baseline: 1.1304x; 1.0353x over previous
//
#include <hip/hip_runtime.h>
#include <hip/hip_bf16.h>

// LoRA transformer: L=8, D=1024, H=16, HD=64, R=16, B=2, S=1024.
// bf16 MFMA everywhere, fp32 residual stream.
// R7: attn -> 512 blocks; merge_T batched over all 8 layers.
// R9: merge_T latency fix (A tile via LDS, independent bv/wv loads).
// R10: attn + gemm64 double-buffered LDS, one barrier/tile; merge_T2 fused.
// R11: merge_T2 load burst pinned with sched_barrier(0) (R9/R10 showed the
// scheduler sinking bv loads back to uses: VGPR stayed 48); vtrans fused into
// gemm_bf16_128 epilogue (V-blocks n0>=2048 write VT transposed directly,
// qkv_bf V-region write dropped), vtrans kernel deleted (-8 dispatches).

typedef unsigned short ushort_t;
typedef __attribute__((ext_vector_type(8))) short bf16x8;
typedef __attribute__((ext_vector_type(4))) float f32x4;

__device__ __forceinline__ unsigned short f2bf(float f) {
    union { float f; unsigned int u; } x; x.f = f;
    unsigned int r = x.u + 0x7fffu + ((x.u >> 16) & 1u);  // RNE
    return (unsigned short)(r >> 16);
}

__device__ __forceinline__ f32x4 mfma16(bf16x8 a, bf16x8 b, f32x4 c) {
    return __builtin_amdgcn_mfma_f32_16x16x32_bf16(a, b, c, 0, 0, 0);
}

typedef const __attribute__((address_space(1))) unsigned int* gas_ptr;
typedef __attribute__((address_space(3))) unsigned int* las_ptr;
// async global->LDS, 16B/lane; LDS dest = wave-uniform base + lane*16 (m104/m108)
__device__ __forceinline__ void lds_stage16(const void* g, void* l) {
    __builtin_amdgcn_global_load_lds((gas_ptr)(unsigned long long)g,
                                     (las_ptr)(unsigned int)(unsigned long long)l,
                                     16, 0, 0);
}

// DPP 16-lane row reductions (row_ror:S = 0x120+S)
#define RORMAX(x, C)                                                           \
    x = fmaxf(x, __int_as_float(__builtin_amdgcn_mov_dpp(                      \
                     __float_as_int(x), C, 0xf, 0xf, false)));
#define RORADD(x, C)                                                           \
    x += __int_as_float(__builtin_amdgcn_mov_dpp(                              \
        __float_as_int(x), C, 0xf, 0xf, false));

// ---------------- x -> (h_f32 copy, h_bf16) ----------------
__global__ __launch_bounds__(256) void convert_x(
    const float4* __restrict__ in, float4* __restrict__ outF,
    ushort4* __restrict__ outB, int n4) {
    int i = blockIdx.x * 256 + threadIdx.x;
    if (i < n4) {
        float4 v = in[i];
        outF[i] = v;
        ushort4 o;
        o.x = f2bf(v.x); o.y = f2bf(v.y); o.z = f2bf(v.z); o.w = f2bf(v.w);
        outB[i] = o;
    }
}

// ------------- LoRA merge + transpose, qkv + proj in ONE dispatch -------------
// blocks 0..6143: qkv (24x32x8); blocks 6144..8191: proj (8x32x8)
// WT[z][n][k] = bf16(W[z][k][n] + A[z][k][:] . B[z][:][n])
__global__ __launch_bounds__(256) void merge_T2(
    const float* __restrict__ Wq, const float* __restrict__ Aq,
    const float* __restrict__ Bq, unsigned short* __restrict__ WTq,
    const float* __restrict__ Wp, const float* __restrict__ Ap,
    const float* __restrict__ Bp, unsigned short* __restrict__ WTp) {
    __shared__ float t[32][132];
    __shared__ float Asl[32][17];  // A tile (32 rows x 16), +1 pad
    int bid = blockIdx.x;
    const float *W, *A, *Bm;
    unsigned short* WT;
    int N, bx, by, bz;
    if (bid < 6144) {
        N = 3072; bx = bid % 24; int u = bid / 24; by = u & 31; bz = u >> 5;
        W = Wq; A = Aq; Bm = Bq; WT = WTq;
    } else {
        bid -= 6144;
        N = 1024; bx = bid & 7; int u = bid >> 3; by = u & 31; bz = u >> 5;
        W = Wp; A = Ap; Bm = Bp; WT = WTp;
    }
    W  += (size_t)bz * 1024 * N;
    A  += (size_t)bz * 1024 * 16;
    Bm += (size_t)bz * 16 * N;
    WT += (size_t)bz * N * 1024;
    int j0 = bx * 128, i0 = by * 32;
    int tx = threadIdx.x & 31, ty = threadIdx.x >> 5;  // 32 x 8

    // Stage A tile cooperatively: 512 floats, 128 threads x float4, coalesced.
    if (threadIdx.x < 128) {
        int r = threadIdx.x >> 2, c4 = (threadIdx.x & 3) * 4;
        float4 a = *(const float4*)&A[(size_t)(i0 + r) * 16 + c4];
        Asl[r][c4 + 0] = a.x; Asl[r][c4 + 1] = a.y;
        Asl[r][c4 + 2] = a.z; Asl[r][c4 + 3] = a.w;
    }
    // Independent global loads: 16 B cols + 4 W rows. sched_barrier(0) pins
    // them all BEFORE any use (R9/R10: scheduler sank them, VGPR stayed 48).
    float4 bv[16];
    #pragma unroll
    for (int r = 0; r < 16; r++)
        bv[r] = *(const float4*)&Bm[(size_t)r * N + j0 + tx * 4];
    float4 wv[4];
    #pragma unroll
    for (int ii0 = 0; ii0 < 4; ii0++)
        wv[ii0] = *(const float4*)&W[(size_t)(i0 + ty + ii0 * 8) * N + j0 + tx * 4];
    __builtin_amdgcn_sched_barrier(0);
    __syncthreads();  // A tile ready (also covers the load latency window)

    #pragma unroll
    for (int ii0 = 0; ii0 < 4; ii0++) {
        int ii = ty + ii0 * 8;
        float4 acc = wv[ii0];
        #pragma unroll
        for (int r = 0; r < 16; r++) {
            float a = Asl[ii][r];  // wave-uniform broadcast read
            acc.x += a * bv[r].x; acc.y += a * bv[r].y;
            acc.z += a * bv[r].z; acc.w += a * bv[r].w;
        }
        *(float4*)&t[ii][tx * 4] = acc;
    }
    __syncthreads();
    int jj = threadIdx.x >> 1, half = threadIdx.x & 1;
    bf16x8 o0, o1;
    #pragma unroll
    for (int c = 0; c < 8; c++) o0[c] = (short)f2bf(t[half * 16 + c][jj]);
    #pragma unroll
    for (int c = 0; c < 8; c++) o1[c] = (short)f2bf(t[half * 16 + 8 + c][jj]);
    unsigned short* dst = &WT[(size_t)(j0 + jj) * 1024 + i0 + half * 16];
    *(bf16x8*)dst = o0;
    *(bf16x8*)(dst + 8) = o1;
}

// --- GEMM 128x128, BK=64; V-blocks (n0>=2048) write VT transposed directly ---
__global__ __launch_bounds__(256) void gemm_bf16_128(
    const unsigned short* __restrict__ A,   // [M][K]
    const unsigned short* __restrict__ BT,  // [N][K]
    unsigned short* __restrict__ outB,      // bf16 out (Q,K regions)
    unsigned short* __restrict__ VT,        // [32][64][1024] transposed V out
    int M, int N, int K) {
    __shared__ __align__(16) unsigned short As[2][128 * 32];
    __shared__ __align__(16) unsigned short Bs[2][128 * 32];
    const int tid = threadIdx.x;
    const int m0 = blockIdx.y * 128, n0 = blockIdx.x * 128;
    const int w = tid >> 6, lane = tid & 63;
    const int wm = (w >> 1) * 64, wn = (w & 1) * 64;
    const int lr = lane & 15, quad = lane >> 4;
    const int srow = w * 16 + (lane >> 2);
    const int skof = (lane & 3) * 8;

    f32x4 acc[4][4] = {};

    for (int k0 = 0; k0 < K; k0 += 64) {
        __syncthreads();
        #pragma unroll
        for (int h = 0; h < 2; h++) {
            lds_stage16(A  + (size_t)(m0 + srow)      * K + k0 + h * 32 + skof,
                        (char*)As[h] + w * 1024);
            lds_stage16(A  + (size_t)(m0 + 64 + srow) * K + k0 + h * 32 + skof,
                        (char*)As[h] + 4096 + w * 1024);
            lds_stage16(BT + (size_t)(n0 + srow)      * K + k0 + h * 32 + skof,
                        (char*)Bs[h] + w * 1024);
            lds_stage16(BT + (size_t)(n0 + 64 + srow) * K + k0 + h * 32 + skof,
                        (char*)Bs[h] + 4096 + w * 1024);
        }
        __syncthreads();

        #pragma unroll
        for (int h = 0; h < 2; h++) {
            bf16x8 af[4], bfr[4];
            #pragma unroll
            for (int i = 0; i < 4; i++) {
                af[i]  = *(const bf16x8*)&As[h][(wm + i * 16 + lr) * 32 + quad * 8];
                bfr[i] = *(const bf16x8*)&Bs[h][(wn + i * 16 + lr) * 32 + quad * 8];
            }
            #pragma unroll
            for (int i = 0; i < 4; i++)
                #pragma unroll
                for (int j = 0; j < 4; j++)
                    acc[i][j] = mfma16(af[i], bfr[j], acc[i][j]);
        }
    }
    if (n0 < 2048) {  // Q,K regions -> qkv_bf (Q cols pre-scaled by 1/8)
        #pragma unroll
        for (int i = 0; i < 4; i++)
            #pragma unroll
            for (int j = 0; j < 4; j++)
                #pragma unroll
                for (int r = 0; r < 4; r++) {
                    int row = m0 + wm + i * 16 + quad * 4 + r;
                    int col = n0 + wn + j * 16 + lr;
                    float v = acc[i][j][r];
                    if (col < 1024) v *= 0.125f;
                    outB[(size_t)row * N + col] = f2bf(v);
                }
    } else {  // V region -> VT[b*1024+hd][s], 4 consecutive s per thread
        const int b = m0 >> 10;
        #pragma unroll
        for (int i = 0; i < 4; i++) {
            int row0 = m0 + wm + i * 16 + quad * 4;
            int s = row0 & 1023;
            #pragma unroll
            for (int j = 0; j < 4; j++) {
                int hd = n0 - 2048 + wn + j * 16 + lr;
                ushort4 o;
                o.x = f2bf(acc[i][j][0]); o.y = f2bf(acc[i][j][1]);
                o.z = f2bf(acc[i][j][2]); o.w = f2bf(acc[i][j][3]);
                *(ushort4*)&VT[((size_t)b * 1024 + hd) * 1024 + s] = o;
            }
        }
    }
}

// ------------- GEMM 64x64 + residual: dbuf LDS, one barrier/tile -------------
__global__ __launch_bounds__(256) void gemm_bf16_64(
    const unsigned short* __restrict__ A,   // [M][K]
    const unsigned short* __restrict__ BT,  // [N][K]
    const float* __restrict__ res,          // [M][N] residual
    float* __restrict__ outF,               // fp32 out
    unsigned short* __restrict__ outB,      // bf16 out
    int M, int N, int K) {
    __shared__ __align__(16) unsigned short As[2][2][64 * 32];  // [buf][half]
    __shared__ __align__(16) unsigned short Bs[2][2][64 * 32];
    const int tid = threadIdx.x;
    const int m0 = blockIdx.y * 64, n0 = blockIdx.x * 64;
    const int w = tid >> 6, lane = tid & 63;
    const int wm = (w >> 1) * 32, wn = (w & 1) * 32;
    const int lr = lane & 15, quad = lane >> 4;
    const int srow = w * 16 + (lane >> 2);
    const int skof = (lane & 3) * 8;

    f32x4 acc[2][2] = {};

    auto stage = [&](int k0, int buf) {
        #pragma unroll
        for (int h = 0; h < 2; h++) {
            lds_stage16(A  + (size_t)(m0 + srow) * K + k0 + h * 32 + skof,
                        (char*)As[buf][h] + w * 1024);
            lds_stage16(BT + (size_t)(n0 + srow) * K + k0 + h * 32 + skof,
                        (char*)Bs[buf][h] + w * 1024);
        }
    };

    const int nk = K >> 6;
    stage(0, 0);
    for (int t = 0; t < nk; t++) {
        __syncthreads();  // drains stage(t) [vmcnt(0)] + prior reads of buf t&1
        if (t + 1 < nk) stage((t + 1) << 6, (t + 1) & 1);
        const int cur = t & 1;
        #pragma unroll
        for (int h = 0; h < 2; h++) {
            bf16x8 af[2], bfr[2];
            #pragma unroll
            for (int i = 0; i < 2; i++) {
                af[i]  = *(const bf16x8*)&As[cur][h][(wm + i * 16 + lr) * 32 + quad * 8];
                bfr[i] = *(const bf16x8*)&Bs[cur][h][(wn + i * 16 + lr) * 32 + quad * 8];
            }
            #pragma unroll
            for (int i = 0; i < 2; i++)
                #pragma unroll
                for (int j = 0; j < 2; j++)
                    acc[i][j] = mfma16(af[i], bfr[j], acc[i][j]);
        }
    }
    #pragma unroll
    for (int i = 0; i < 2; i++)
        #pragma unroll
        for (int j = 0; j < 2; j++)
            #pragma unroll
            for (int r = 0; r < 4; r++) {
                int row = m0 + wm + i * 16 + quad * 4 + r;
                int col = n0 + wn + j * 16 + lr;
                float v = acc[i][j][r] + res[(size_t)row * N + col];
                if (outF) outF[(size_t)row * N + col] = v;
                if (outB) outB[(size_t)row * N + col] = f2bf(v);
            }
}

// ------------- Flash attention: dbuf K/V staging, one barrier/tile -------------
// 512 blocks, one 64-row q-block each; qblk = bh<16 ? x : 15-x.
__global__ __launch_bounds__(256) void attn_kernel(
    const unsigned short* __restrict__ qkv,  // [2048][3072]
    const unsigned short* __restrict__ VT,   // [32][64][1024]
    unsigned short* __restrict__ O) {        // [2048][1024]
    __shared__ __align__(16) unsigned short Ks[2][2][64 * 32];  // [buf][dhalf][s][d32]
    __shared__ __align__(16) unsigned short Vs[2][2][64 * 32];  // [buf][shalf][d][s32]
    __shared__ __align__(16) unsigned short pl[4][16 * 72];
    const int tid = threadIdx.x;
    const int w = tid >> 6, lane = tid & 63;
    const int lr = lane & 15, quad = lane >> 4;
    const int bh = blockIdx.y, b = bh >> 4, h = bh & 15;
    const int qblk = (bh < 16) ? blockIdx.x : (15 - blockIdx.x);
    const int qb = qblk * 64 + w * 16;
    const int srow = w * 16 + (lane >> 2);
    const int skof = (lane & 3) * 8;
    const float LOG2E = 1.44269504f;

    const size_t rowQ = (size_t)(b * 1024 + qb + lr) * 3072 + h * 64;
    bf16x8 aq0 = *(const bf16x8*)&qkv[rowQ + quad * 8];
    bf16x8 aq1 = *(const bf16x8*)&qkv[rowQ + 32 + quad * 8];

    float m_i[4], l_i[4];
    f32x4 oacc[4] = {};
    #pragma unroll
    for (int r = 0; r < 4; r++) { m_i[r] = -1e30f; l_i[r] = 0.f; }

    auto stage = [&](int kt64, int buf) {
        const int kt = kt64 << 6;
        const size_t gK = (size_t)(b * 1024 + kt + srow) * 3072 + 1024 + h * 64;
        lds_stage16(qkv + gK + skof,      (char*)Ks[buf][0] + w * 1024);
        lds_stage16(qkv + gK + 32 + skof, (char*)Ks[buf][1] + w * 1024);
        const size_t gV = ((size_t)bh * 64 + srow) * 1024 + kt;
        lds_stage16(VT + gV + skof,       (char*)Vs[buf][0] + w * 1024);
        lds_stage16(VT + gV + 32 + skof,  (char*)Vs[buf][1] + w * 1024);
    };

    const int nkt = qblk + 1;  // k-tiles of 64
    stage(0, 0);
    for (int kt64 = 0; kt64 < nkt; kt64++) {
        __syncthreads();  // drains stage(kt64); prior reads of next buf done
        if (kt64 + 1 < nkt) stage(kt64 + 1, (kt64 + 1) & 1);
        const int cur = kt64 & 1;
        const int kt = kt64 << 6;

        // QK^T: 16 q-rows x 64 k-cols
        f32x4 s[4] = {};
        #pragma unroll
        for (int nh = 0; nh < 4; nh++) {
            bf16x8 kb0 = *(const bf16x8*)&Ks[cur][0][(nh * 16 + lr) * 32 + quad * 8];
            bf16x8 kb1 = *(const bf16x8*)&Ks[cur][1][(nh * 16 + lr) * 32 + quad * 8];
            s[nh] = mfma16(aq0, kb0, s[nh]);
            s[nh] = mfma16(aq1, kb1, s[nh]);
        }
        float mx[4];
        if (kt + 64 > qb) {  // diagonal tile: causal mask
            #pragma unroll
            for (int r = 0; r < 4; r++) {
                int qrow = qb + quad * 4 + r;
                #pragma unroll
                for (int nh = 0; nh < 4; nh++) {
                    int kcol = kt + nh * 16 + lr;
                    s[nh][r] = (kcol <= qrow) ? s[nh][r] : -1e30f;
                }
            }
        }
        #pragma unroll
        for (int r = 0; r < 4; r++) {
            mx[r] = fmaxf(fmaxf(s[0][r], s[1][r]), fmaxf(s[2][r], s[3][r]));
            RORMAX(mx[r], 0x121) RORMAX(mx[r], 0x122)
            RORMAX(mx[r], 0x124) RORMAX(mx[r], 0x128)
        }
        float al[4];
        #pragma unroll
        for (int r = 0; r < 4; r++) {
            float mnew = fmaxf(m_i[r], mx[r]);
            al[r] = exp2f((m_i[r] - mnew) * LOG2E);
            m_i[r] = mnew;
            float lsum = 0.f;
            #pragma unroll
            for (int nh = 0; nh < 4; nh++) {
                float p = exp2f((s[nh][r] - mnew) * LOG2E);
                s[nh][r] = p;
                lsum += p;
            }
            l_i[r] = l_i[r] * al[r] + lsum;  // lane-local partial
        }
        #pragma unroll
        for (int dt = 0; dt < 4; dt++)
            #pragma unroll
            for (int r = 0; r < 4; r++) oacc[dt][r] *= al[r];
        // P: C-layout -> LDS -> A-layout (wave-internal)
        #pragma unroll
        for (int nh = 0; nh < 4; nh++)
            #pragma unroll
            for (int r = 0; r < 4; r++)
                pl[w][(quad * 4 + r) * 72 + nh * 16 + lr] = f2bf(s[nh][r]);
        bf16x8 ap0 = *(const bf16x8*)&pl[w][lr * 72 + quad * 8];
        bf16x8 ap1 = *(const bf16x8*)&pl[w][lr * 72 + 32 + quad * 8];
        #pragma unroll
        for (int dt = 0; dt < 4; dt++) {
            bf16x8 vb0 = *(const bf16x8*)&Vs[cur][0][(dt * 16 + lr) * 32 + quad * 8];
            bf16x8 vb1 = *(const bf16x8*)&Vs[cur][1][(dt * 16 + lr) * 32 + quad * 8];
            oacc[dt] = mfma16(ap0, vb0, oacc[dt]);
            oacc[dt] = mfma16(ap1, vb1, oacc[dt]);
        }
    }
    // cross-lane finish of l (16 col-lanes per row group)
    #pragma unroll
    for (int r = 0; r < 4; r++) {
        RORADD(l_i[r], 0x121) RORADD(l_i[r], 0x122)
        RORADD(l_i[r], 0x124) RORADD(l_i[r], 0x128)
    }
    #pragma unroll
    for (int dt = 0; dt < 4; dt++)
        #pragma unroll
        for (int r = 0; r < 4; r++) {
            int row = b * 1024 + qb + quad * 4 + r;
            int col = h * 64 + dt * 16 + lr;
            O[(size_t)row * 1024 + col] = f2bf(oacc[dt][r] / l_i[r]);
        }
}

extern "C" void kernel_launch(void* const* d_in, const int* in_sizes, int n_in,
                              void* d_out, int out_size, void* d_ws, size_t ws_size,
                              hipStream_t stream) {
    const float* x     = (const float*)d_in[0];
    const float* Wqkv  = (const float*)d_in[1];
    const float* Aqkv  = (const float*)d_in[2];
    const float* Bqkv  = (const float*)d_in[3];
    const float* Wproj = (const float*)d_in[4];
    const float* Aproj = (const float*)d_in[5];
    const float* Bproj = (const float*)d_in[6];
    float* out = (float*)d_out;

    char* ws = (char*)d_ws;
    float* h_f32 = (float*)ws;                    ws += (size_t)2048 * 1024 * 4;
    unsigned short* h_bf   = (unsigned short*)ws; ws += (size_t)2048 * 1024 * 2;
    unsigned short* qkv_bf = (unsigned short*)ws; ws += (size_t)2048 * 3072 * 2;
    unsigned short* VT     = (unsigned short*)ws; ws += (size_t)32 * 64 * 1024 * 2;
    unsigned short* O_bf   = (unsigned short*)ws; ws += (size_t)2048 * 1024 * 2;
    unsigned short* WqT8   = (unsigned short*)ws; ws += (size_t)8 * 3072 * 1024 * 2;
    unsigned short* WpT8   = (unsigned short*)ws; ws += (size_t)8 * 1024 * 1024 * 2;

    convert_x<<<2048, 256, 0, stream>>>((const float4*)x, (float4*)h_f32,
                                        (ushort4*)h_bf, 2048 * 1024 / 4);
    // all layers' LoRA merges up front (independent of activations), one dispatch
    merge_T2<<<8192, 256, 0, stream>>>(Wqkv, Aqkv, Bqkv, WqT8,
                                       Wproj, Aproj, Bproj, WpT8);

    for (int l = 0; l < 8; l++) {
        const unsigned short* WqT = WqT8 + (size_t)l * 3072 * 1024;
        const unsigned short* WpT = WpT8 + (size_t)l * 1024 * 1024;
        // qkv GEMM: Q cols pre-scaled 1/8; V cols written transposed to VT
        gemm_bf16_128<<<dim3(24, 16), 256, 0, stream>>>(h_bf, WqT, qkv_bf, VT,
                                                        2048, 3072, 1024);
        attn_kernel<<<dim3(16, 32), 256, 0, stream>>>(qkv_bf, VT, O_bf);
        float* outF = (l == 7) ? out : h_f32;
        gemm_bf16_64<<<dim3(16, 32), 256, 0, stream>>>(O_bf, WpT, h_f32, outF,
                                                       h_bf, 2048, 1024, 1024);
    }
}

// Round 5
// 710.039 us; speedup vs baseline: 1.1414x; 1.0098x over previous
//
#include <hip/hip_runtime.h>
#include <hip/hip_bf16.h>

// LoRA transformer: L=8, D=1024, H=16, HD=64, R=16, B=2, S=1024.
// bf16 MFMA everywhere, fp32 residual stream.
// R7: attn -> 512 blocks; merge_T batched over all 8 layers.
// R10: attn + gemm64 double-buffered LDS, one barrier/tile; merge_T2 fused.
// R11: vtrans fused into gemm_bf16_128 epilogue (V written transposed).
// R12: merge_T2 rewritten: W tile DMA'd to LDS (off the register latency
// chain entirely); LoRA term computed directly in transposed layout (t-buffer
// + 2 barriers + acc round-trip deleted; only latency loads left are 16
// independent L2-hot B-column dwords). attn: LOG2E folded into Q pre-scale
// (exp2f(s-m) directly, ~20 v_mul/tile removed from softmax path).

typedef unsigned short ushort_t;
typedef __attribute__((ext_vector_type(8))) short bf16x8;
typedef __attribute__((ext_vector_type(4))) float f32x4;

__device__ __forceinline__ unsigned short f2bf(float f) {
    union { float f; unsigned int u; } x; x.f = f;
    unsigned int r = x.u + 0x7fffu + ((x.u >> 16) & 1u);  // RNE
    return (unsigned short)(r >> 16);
}

__device__ __forceinline__ f32x4 mfma16(bf16x8 a, bf16x8 b, f32x4 c) {
    return __builtin_amdgcn_mfma_f32_16x16x32_bf16(a, b, c, 0, 0, 0);
}

typedef const __attribute__((address_space(1))) unsigned int* gas_ptr;
typedef __attribute__((address_space(3))) unsigned int* las_ptr;
// async global->LDS, 16B/lane; LDS dest = wave-uniform base + lane*16 (m104/m108)
__device__ __forceinline__ void lds_stage16(const void* g, void* l) {
    __builtin_amdgcn_global_load_lds((gas_ptr)(unsigned long long)g,
                                     (las_ptr)(unsigned int)(unsigned long long)l,
                                     16, 0, 0);
}

// DPP 16-lane row reductions (row_ror:S = 0x120+S)
#define RORMAX(x, C)                                                           \
    x = fmaxf(x, __int_as_float(__builtin_amdgcn_mov_dpp(                      \
                     __float_as_int(x), C, 0xf, 0xf, false)));
#define RORADD(x, C)                                                           \
    x += __int_as_float(__builtin_amdgcn_mov_dpp(                              \
        __float_as_int(x), C, 0xf, 0xf, false));

// ---------------- x -> (h_f32 copy, h_bf16) ----------------
__global__ __launch_bounds__(256) void convert_x(
    const float4* __restrict__ in, float4* __restrict__ outF,
    ushort4* __restrict__ outB, int n4) {
    int i = blockIdx.x * 256 + threadIdx.x;
    if (i < n4) {
        float4 v = in[i];
        outF[i] = v;
        ushort4 o;
        o.x = f2bf(v.x); o.y = f2bf(v.y); o.z = f2bf(v.z); o.w = f2bf(v.w);
        outB[i] = o;
    }
}

// ------------- LoRA merge + transpose, qkv + proj in ONE dispatch -------------
// blocks 0..6143: qkv (24x32x8); blocks 6144..8191: proj (8x32x8)
// WT[z][n][k] = bf16(W[z][k][n] + A[z][k][:] . B[z][:][n])
// W tile -> LDS via DMA; lora computed in transposed layout; B column in regs.
__global__ __launch_bounds__(256) void merge_T2(
    const float* __restrict__ Wq, const float* __restrict__ Aq,
    const float* __restrict__ Bq, unsigned short* __restrict__ WTq,
    const float* __restrict__ Wp, const float* __restrict__ Ap,
    const float* __restrict__ Bp, unsigned short* __restrict__ WTp) {
    __shared__ float Asl[32][17];                 // A tile (32 rows x 16), +1 pad
    __shared__ __align__(16) float tW[32 * 128];  // W tile, DMA'd, linear
    int bid = blockIdx.x;
    const float *W, *A, *Bm;
    unsigned short* WT;
    int N, bx, by, bz;
    if (bid < 6144) {
        N = 3072; bx = bid % 24; int u = bid / 24; by = u & 31; bz = u >> 5;
        W = Wq; A = Aq; Bm = Bq; WT = WTq;
    } else {
        bid -= 6144;
        N = 1024; bx = bid & 7; int u = bid >> 3; by = u & 31; bz = u >> 5;
        W = Wp; A = Ap; Bm = Bp; WT = WTp;
    }
    W  += (size_t)bz * 1024 * N;
    A  += (size_t)bz * 1024 * 16;
    Bm += (size_t)bz * 16 * N;
    WT += (size_t)bz * N * 1024;
    const int j0 = bx * 128, i0 = by * 32;
    const int tid = threadIdx.x;
    const int w = tid >> 6, lane = tid & 63;

    // DMA W tile (32x128 f32 = 16KB) -> LDS. 4 stage16 per thread; each wave
    // instruction stages 2 rows (64 lanes x 16B). No VGPR round-trip.
    #pragma unroll
    for (int s = 0; s < 4; s++) {
        int w4s = w * 4 + s;                       // 0..15 -> row pair
        int tr = w4s * 2 + (lane >> 5);            // tile row 0..31
        lds_stage16(W + (size_t)(i0 + tr) * N + j0 + (lane & 31) * 4,
                    (char*)tW + w4s * 1024);
    }
    // Stage A tile cooperatively: 512 floats, 128 threads x float4, coalesced.
    if (tid < 128) {
        int r = tid >> 2, c4 = (tid & 3) * 4;
        float4 a = *(const float4*)&A[(size_t)(i0 + r) * 16 + c4];
        Asl[r][c4 + 0] = a.x; Asl[r][c4 + 1] = a.y;
        Asl[r][c4 + 2] = a.z; Asl[r][c4 + 3] = a.w;
    }
    // B column for this thread's output row: 16 independent dwords, L2-hot.
    const int jj = tid >> 1, half = tid & 1;
    float bcol[16];
    #pragma unroll
    for (int r = 0; r < 16; r++)
        bcol[r] = Bm[(size_t)r * N + j0 + jj];
    __builtin_amdgcn_sched_barrier(0);
    __syncthreads();  // drains W DMA (vmcnt) + A stage

    // 16 output values: rows i0+half*16+c, col j0+jj; transposed store.
    bf16x8 o0, o1;
    #pragma unroll
    for (int c = 0; c < 16; c++) {
        int rloc = half * 16 + c;
        float v = tW[rloc * 128 + jj];             // bank=jj%32: 2-way, free
        #pragma unroll
        for (int r = 0; r < 16; r++)
            v += Asl[rloc][r] * bcol[r];           // Asl: 2-addr broadcast
        unsigned short b = f2bf(v);
        if (c < 8) o0[c] = (short)b; else o1[c - 8] = (short)b;
    }
    unsigned short* dst = &WT[(size_t)(j0 + jj) * 1024 + i0 + half * 16];
    *(bf16x8*)dst = o0;
    *(bf16x8*)(dst + 8) = o1;
}

// --- GEMM 128x128, BK=64; V-blocks (n0>=2048) write VT transposed directly ---
__global__ __launch_bounds__(256) void gemm_bf16_128(
    const unsigned short* __restrict__ A,   // [M][K]
    const unsigned short* __restrict__ BT,  // [N][K]
    unsigned short* __restrict__ outB,      // bf16 out (Q,K regions)
    unsigned short* __restrict__ VT,        // [32][64][1024] transposed V out
    int M, int N, int K) {
    __shared__ __align__(16) unsigned short As[2][128 * 32];
    __shared__ __align__(16) unsigned short Bs[2][128 * 32];
    const int tid = threadIdx.x;
    const int m0 = blockIdx.y * 128, n0 = blockIdx.x * 128;
    const int w = tid >> 6, lane = tid & 63;
    const int wm = (w >> 1) * 64, wn = (w & 1) * 64;
    const int lr = lane & 15, quad = lane >> 4;
    const int srow = w * 16 + (lane >> 2);
    const int skof = (lane & 3) * 8;

    f32x4 acc[4][4] = {};

    for (int k0 = 0; k0 < K; k0 += 64) {
        __syncthreads();
        #pragma unroll
        for (int h = 0; h < 2; h++) {
            lds_stage16(A  + (size_t)(m0 + srow)      * K + k0 + h * 32 + skof,
                        (char*)As[h] + w * 1024);
            lds_stage16(A  + (size_t)(m0 + 64 + srow) * K + k0 + h * 32 + skof,
                        (char*)As[h] + 4096 + w * 1024);
            lds_stage16(BT + (size_t)(n0 + srow)      * K + k0 + h * 32 + skof,
                        (char*)Bs[h] + w * 1024);
            lds_stage16(BT + (size_t)(n0 + 64 + srow) * K + k0 + h * 32 + skof,
                        (char*)Bs[h] + 4096 + w * 1024);
        }
        __syncthreads();

        #pragma unroll
        for (int h = 0; h < 2; h++) {
            bf16x8 af[4], bfr[4];
            #pragma unroll
            for (int i = 0; i < 4; i++) {
                af[i]  = *(const bf16x8*)&As[h][(wm + i * 16 + lr) * 32 + quad * 8];
                bfr[i] = *(const bf16x8*)&Bs[h][(wn + i * 16 + lr) * 32 + quad * 8];
            }
            #pragma unroll
            for (int i = 0; i < 4; i++)
                #pragma unroll
                for (int j = 0; j < 4; j++)
                    acc[i][j] = mfma16(af[i], bfr[j], acc[i][j]);
        }
    }
    if (n0 < 2048) {  // Q,K regions -> qkv_bf (Q cols pre-scaled by log2e/8)
        #pragma unroll
        for (int i = 0; i < 4; i++)
            #pragma unroll
            for (int j = 0; j < 4; j++)
                #pragma unroll
                for (int r = 0; r < 4; r++) {
                    int row = m0 + wm + i * 16 + quad * 4 + r;
                    int col = n0 + wn + j * 16 + lr;
                    float v = acc[i][j][r];
                    if (col < 1024) v *= 0.125f * 1.44269504f;  // 1/sqrt(64)*log2e
                    outB[(size_t)row * N + col] = f2bf(v);
                }
    } else {  // V region -> VT[b*1024+hd][s], 4 consecutive s per thread
        const int b = m0 >> 10;
        #pragma unroll
        for (int i = 0; i < 4; i++) {
            int row0 = m0 + wm + i * 16 + quad * 4;
            int s = row0 & 1023;
            #pragma unroll
            for (int j = 0; j < 4; j++) {
                int hd = n0 - 2048 + wn + j * 16 + lr;
                ushort4 o;
                o.x = f2bf(acc[i][j][0]); o.y = f2bf(acc[i][j][1]);
                o.z = f2bf(acc[i][j][2]); o.w = f2bf(acc[i][j][3]);
                *(ushort4*)&VT[((size_t)b * 1024 + hd) * 1024 + s] = o;
            }
        }
    }
}

// ------------- GEMM 64x64 + residual: dbuf LDS, one barrier/tile -------------
__global__ __launch_bounds__(256) void gemm_bf16_64(
    const unsigned short* __restrict__ A,   // [M][K]
    const unsigned short* __restrict__ BT,  // [N][K]
    const float* __restrict__ res,          // [M][N] residual
    float* __restrict__ outF,               // fp32 out
    unsigned short* __restrict__ outB,      // bf16 out
    int M, int N, int K) {
    __shared__ __align__(16) unsigned short As[2][2][64 * 32];  // [buf][half]
    __shared__ __align__(16) unsigned short Bs[2][2][64 * 32];
    const int tid = threadIdx.x;
    const int m0 = blockIdx.y * 64, n0 = blockIdx.x * 64;
    const int w = tid >> 6, lane = tid & 63;
    const int wm = (w >> 1) * 32, wn = (w & 1) * 32;
    const int lr = lane & 15, quad = lane >> 4;
    const int srow = w * 16 + (lane >> 2);
    const int skof = (lane & 3) * 8;

    f32x4 acc[2][2] = {};

    auto stage = [&](int k0, int buf) {
        #pragma unroll
        for (int h = 0; h < 2; h++) {
            lds_stage16(A  + (size_t)(m0 + srow) * K + k0 + h * 32 + skof,
                        (char*)As[buf][h] + w * 1024);
            lds_stage16(BT + (size_t)(n0 + srow) * K + k0 + h * 32 + skof,
                        (char*)Bs[buf][h] + w * 1024);
        }
    };

    const int nk = K >> 6;
    stage(0, 0);
    for (int t = 0; t < nk; t++) {
        __syncthreads();  // drains stage(t) [vmcnt(0)] + prior reads of buf t&1
        if (t + 1 < nk) stage((t + 1) << 6, (t + 1) & 1);
        const int cur = t & 1;
        #pragma unroll
        for (int h = 0; h < 2; h++) {
            bf16x8 af[2], bfr[2];
            #pragma unroll
            for (int i = 0; i < 2; i++) {
                af[i]  = *(const bf16x8*)&As[cur][h][(wm + i * 16 + lr) * 32 + quad * 8];
                bfr[i] = *(const bf16x8*)&Bs[cur][h][(wn + i * 16 + lr) * 32 + quad * 8];
            }
            #pragma unroll
            for (int i = 0; i < 2; i++)
                #pragma unroll
                for (int j = 0; j < 2; j++)
                    acc[i][j] = mfma16(af[i], bfr[j], acc[i][j]);
        }
    }
    #pragma unroll
    for (int i = 0; i < 2; i++)
        #pragma unroll
        for (int j = 0; j < 2; j++)
            #pragma unroll
            for (int r = 0; r < 4; r++) {
                int row = m0 + wm + i * 16 + quad * 4 + r;
                int col = n0 + wn + j * 16 + lr;
                float v = acc[i][j][r] + res[(size_t)row * N + col];
                if (outF) outF[(size_t)row * N + col] = v;
                if (outB) outB[(size_t)row * N + col] = f2bf(v);
            }
}

// ------------- Flash attention: dbuf K/V staging, one barrier/tile -------------
// 512 blocks, one 64-row q-block each; qblk = bh<16 ? x : 15-x.
// Scores arrive already in log2 domain (Q pre-scaled by log2e/8 in gemm128).
__global__ __launch_bounds__(256) void attn_kernel(
    const unsigned short* __restrict__ qkv,  // [2048][3072]
    const unsigned short* __restrict__ VT,   // [32][64][1024]
    unsigned short* __restrict__ O) {        // [2048][1024]
    __shared__ __align__(16) unsigned short Ks[2][2][64 * 32];  // [buf][dhalf][s][d32]
    __shared__ __align__(16) unsigned short Vs[2][2][64 * 32];  // [buf][shalf][d][s32]
    __shared__ __align__(16) unsigned short pl[4][16 * 72];
    const int tid = threadIdx.x;
    const int w = tid >> 6, lane = tid & 63;
    const int lr = lane & 15, quad = lane >> 4;
    const int bh = blockIdx.y, b = bh >> 4, h = bh & 15;
    const int qblk = (bh < 16) ? blockIdx.x : (15 - blockIdx.x);
    const int qb = qblk * 64 + w * 16;
    const int srow = w * 16 + (lane >> 2);
    const int skof = (lane & 3) * 8;

    const size_t rowQ = (size_t)(b * 1024 + qb + lr) * 3072 + h * 64;
    bf16x8 aq0 = *(const bf16x8*)&qkv[rowQ + quad * 8];
    bf16x8 aq1 = *(const bf16x8*)&qkv[rowQ + 32 + quad * 8];

    float m_i[4], l_i[4];
    f32x4 oacc[4] = {};
    #pragma unroll
    for (int r = 0; r < 4; r++) { m_i[r] = -1e30f; l_i[r] = 0.f; }

    auto stage = [&](int kt64, int buf) {
        const int kt = kt64 << 6;
        const size_t gK = (size_t)(b * 1024 + kt + srow) * 3072 + 1024 + h * 64;
        lds_stage16(qkv + gK + skof,      (char*)Ks[buf][0] + w * 1024);
        lds_stage16(qkv + gK + 32 + skof, (char*)Ks[buf][1] + w * 1024);
        const size_t gV = ((size_t)bh * 64 + srow) * 1024 + kt;
        lds_stage16(VT + gV + skof,       (char*)Vs[buf][0] + w * 1024);
        lds_stage16(VT + gV + 32 + skof,  (char*)Vs[buf][1] + w * 1024);
    };

    const int nkt = qblk + 1;  // k-tiles of 64
    stage(0, 0);
    for (int kt64 = 0; kt64 < nkt; kt64++) {
        __syncthreads();  // drains stage(kt64); prior reads of next buf done
        if (kt64 + 1 < nkt) stage(kt64 + 1, (kt64 + 1) & 1);
        const int cur = kt64 & 1;
        const int kt = kt64 << 6;

        // QK^T: 16 q-rows x 64 k-cols (already log2-scaled)
        f32x4 s[4] = {};
        #pragma unroll
        for (int nh = 0; nh < 4; nh++) {
            bf16x8 kb0 = *(const bf16x8*)&Ks[cur][0][(nh * 16 + lr) * 32 + quad * 8];
            bf16x8 kb1 = *(const bf16x8*)&Ks[cur][1][(nh * 16 + lr) * 32 + quad * 8];
            s[nh] = mfma16(aq0, kb0, s[nh]);
            s[nh] = mfma16(aq1, kb1, s[nh]);
        }
        float mx[4];
        if (kt + 64 > qb) {  // diagonal tile: causal mask
            #pragma unroll
            for (int r = 0; r < 4; r++) {
                int qrow = qb + quad * 4 + r;
                #pragma unroll
                for (int nh = 0; nh < 4; nh++) {
                    int kcol = kt + nh * 16 + lr;
                    s[nh][r] = (kcol <= qrow) ? s[nh][r] : -1e30f;
                }
            }
        }
        #pragma unroll
        for (int r = 0; r < 4; r++) {
            mx[r] = fmaxf(fmaxf(s[0][r], s[1][r]), fmaxf(s[2][r], s[3][r]));
            RORMAX(mx[r], 0x121) RORMAX(mx[r], 0x122)
            RORMAX(mx[r], 0x124) RORMAX(mx[r], 0x128)
        }
        float al[4];
        #pragma unroll
        for (int r = 0; r < 4; r++) {
            float mnew = fmaxf(m_i[r], mx[r]);
            al[r] = exp2f(m_i[r] - mnew);
            m_i[r] = mnew;
            float lsum = 0.f;
            #pragma unroll
            for (int nh = 0; nh < 4; nh++) {
                float p = exp2f(s[nh][r] - mnew);
                s[nh][r] = p;
                lsum += p;
            }
            l_i[r] = l_i[r] * al[r] + lsum;  // lane-local partial
        }
        #pragma unroll
        for (int dt = 0; dt < 4; dt++)
            #pragma unroll
            for (int r = 0; r < 4; r++) oacc[dt][r] *= al[r];
        // P: C-layout -> LDS -> A-layout (wave-internal)
        #pragma unroll
        for (int nh = 0; nh < 4; nh++)
            #pragma unroll
            for (int r = 0; r < 4; r++)
                pl[w][(quad * 4 + r) * 72 + nh * 16 + lr] = f2bf(s[nh][r]);
        bf16x8 ap0 = *(const bf16x8*)&pl[w][lr * 72 + quad * 8];
        bf16x8 ap1 = *(const bf16x8*)&pl[w][lr * 72 + 32 + quad * 8];
        #pragma unroll
        for (int dt = 0; dt < 4; dt++) {
            bf16x8 vb0 = *(const bf16x8*)&Vs[cur][0][(dt * 16 + lr) * 32 + quad * 8];
            bf16x8 vb1 = *(const bf16x8*)&Vs[cur][1][(dt * 16 + lr) * 32 + quad * 8];
            oacc[dt] = mfma16(ap0, vb0, oacc[dt]);
            oacc[dt] = mfma16(ap1, vb1, oacc[dt]);
        }
    }
    // cross-lane finish of l (16 col-lanes per row group)
    #pragma unroll
    for (int r = 0; r < 4; r++) {
        RORADD(l_i[r], 0x121) RORADD(l_i[r], 0x122)
        RORADD(l_i[r], 0x124) RORADD(l_i[r], 0x128)
    }
    #pragma unroll
    for (int dt = 0; dt < 4; dt++)
        #pragma unroll
        for (int r = 0; r < 4; r++) {
            int row = b * 1024 + qb + quad * 4 + r;
            int col = h * 64 + dt * 16 + lr;
            O[(size_t)row * 1024 + col] = f2bf(oacc[dt][r] / l_i[r]);
        }
}

extern "C" void kernel_launch(void* const* d_in, const int* in_sizes, int n_in,
                              void* d_out, int out_size, void* d_ws, size_t ws_size,
                              hipStream_t stream) {
    const float* x     = (const float*)d_in[0];
    const float* Wqkv  = (const float*)d_in[1];
    const float* Aqkv  = (const float*)d_in[2];
    const float* Bqkv  = (const float*)d_in[3];
    const float* Wproj = (const float*)d_in[4];
    const float* Aproj = (const float*)d_in[5];
    const float* Bproj = (const float*)d_in[6];
    float* out = (float*)d_out;

    char* ws = (char*)d_ws;
    float* h_f32 = (float*)ws;                    ws += (size_t)2048 * 1024 * 4;
    unsigned short* h_bf   = (unsigned short*)ws; ws += (size_t)2048 * 1024 * 2;
    unsigned short* qkv_bf = (unsigned short*)ws; ws += (size_t)2048 * 3072 * 2;
    unsigned short* VT     = (unsigned short*)ws; ws += (size_t)32 * 64 * 1024 * 2;
    unsigned short* O_bf   = (unsigned short*)ws; ws += (size_t)2048 * 1024 * 2;
    unsigned short* WqT8   = (unsigned short*)ws; ws += (size_t)8 * 3072 * 1024 * 2;
    unsigned short* WpT8   = (unsigned short*)ws; ws += (size_t)8 * 1024 * 1024 * 2;

    convert_x<<<2048, 256, 0, stream>>>((const float4*)x, (float4*)h_f32,
                                        (ushort4*)h_bf, 2048 * 1024 / 4);
    // all layers' LoRA merges up front (independent of activations), one dispatch
    merge_T2<<<8192, 256, 0, stream>>>(Wqkv, Aqkv, Bqkv, WqT8,
                                       Wproj, Aproj, Bproj, WpT8);

    for (int l = 0; l < 8; l++) {
        const unsigned short* WqT = WqT8 + (size_t)l * 3072 * 1024;
        const unsigned short* WpT = WpT8 + (size_t)l * 1024 * 1024;
        // qkv GEMM: Q cols pre-scaled log2e/8; V cols written transposed to VT
        gemm_bf16_128<<<dim3(24, 16), 256, 0, stream>>>(h_bf, WqT, qkv_bf, VT,
                                                        2048, 3072, 1024);
        attn_kernel<<<dim3(16, 32), 256, 0, stream>>>(qkv_bf, VT, O_bf);
        float* outF = (l == 7) ? out : h_f32;
        gemm_bf16_64<<<dim3(16, 32), 256, 0, stream>>>(O_bf, WpT, h_f32, outF,
                                                       h_bf, 2048, 1024, 1024);
    }
}